// Round 10
// baseline (417.976 us; speedup 1.0000x reference)
//
#include <hip/hip_runtime.h>
#include <cstdint>
#include <cstddef>

#define N_NODES 50000
#define N_EDGES 800000
#define ET (N_EDGES + N_NODES)   // edges + self loops
#define D 128
#define NLAYERS 3
#define SLOPE 0.2f
#define NB_SCAN ((N_NODES + 1023) / 1024)   // 49 blocks

typedef __bf16 bf16x8 __attribute__((ext_vector_type(8)));
typedef float  f32x4  __attribute__((ext_vector_type(4)));
typedef float  f32x2  __attribute__((ext_vector_type(2)));

// ---- bf16 split helpers (round-to-nearest-even) ----
__device__ __forceinline__ unsigned short f2bf_rne(float v) {
    unsigned u = __float_as_uint(v);
    u += 0x7fffu + ((u >> 16) & 1u);
    return (unsigned short)(u >> 16);
}
__device__ __forceinline__ float bf2f(unsigned short h) {
    return __uint_as_float(((unsigned)h) << 16);
}
__device__ __forceinline__ f32x2 unpack_bf2(unsigned u) {
    f32x2 r;
    r.x = __uint_as_float(u << 16);
    r.y = __uint_as_float(u & 0xffff0000u);
    return r;
}

// ===== merged prep: split x -> bf16 hi/lo, transpose+split weights, degree count =====
__global__ void prep_kernel(const float* __restrict__ x,
                            const float* __restrict__ Wl,
                            const float* __restrict__ Wr,
                            const int* __restrict__ dstp,
                            unsigned short* __restrict__ hhi,
                            unsigned short* __restrict__ hlo,
                            unsigned short* __restrict__ wlh,
                            unsigned short* __restrict__ wll,
                            unsigned short* __restrict__ wrh,
                            int* __restrict__ deg)
{
    int idx = blockIdx.x * blockDim.x + threadIdx.x;
    if (idx < (N_NODES * D) / 4) {
        float4 v = ((const float4*)x)[idx];
        unsigned short h0 = f2bf_rne(v.x), h1 = f2bf_rne(v.y);
        unsigned short h2 = f2bf_rne(v.z), h3 = f2bf_rne(v.w);
        unsigned short l0 = f2bf_rne(v.x - bf2f(h0)), l1 = f2bf_rne(v.y - bf2f(h1));
        unsigned short l2 = f2bf_rne(v.z - bf2f(h2)), l3 = f2bf_rne(v.w - bf2f(h3));
        uint2 hw, lw;
        hw.x = (unsigned)h0 | ((unsigned)h1 << 16);
        hw.y = (unsigned)h2 | ((unsigned)h3 << 16);
        lw.x = (unsigned)l0 | ((unsigned)l1 << 16);
        lw.y = (unsigned)l2 | ((unsigned)l3 << 16);
        ((uint2*)hhi)[idx] = hw;
        ((uint2*)hlo)[idx] = lw;
    }
    if (idx < NLAYERS * D * D) {
        int l   = idx / (D * D);
        int rem = idx - l * D * D;
        int kk  = rem / D;
        int nn  = rem - kk * D;
        int tp  = l * D * D + nn * D + kk;
        float v = Wl[idx];
        unsigned short h = f2bf_rne(v);
        wlh[tp] = h;
        wll[tp] = f2bf_rne(v - bf2f(h));
        wrh[tp] = f2bf_rne(Wr[idx]);
    }
    if (idx < ET) {
        int dt = (idx < N_EDGES) ? dstp[idx] : idx - N_EDGES;
        atomicAdd(deg + dt, 1);
    }
}

// ================= CSR build ==================
__global__ void scan1_kernel(const int* __restrict__ deg,
                             int* __restrict__ incl, int* __restrict__ bsum)
{
    __shared__ int tmp[1024];
    int tid = threadIdx.x;
    int i = blockIdx.x * 1024 + tid;
    int v = (i < N_NODES) ? deg[i] : 0;
    tmp[tid] = v;
    __syncthreads();
    #pragma unroll
    for (int o = 1; o < 1024; o <<= 1) {
        int t = (tid >= o) ? tmp[tid - o] : 0;
        __syncthreads();
        tmp[tid] += t;
        __syncthreads();
    }
    if (i < N_NODES) incl[i] = tmp[tid];
    if (tid == 1023) bsum[blockIdx.x] = tmp[1023];
}

__global__ void scan3_kernel(const int* __restrict__ deg, const int* __restrict__ incl,
                             const int* __restrict__ bsum,
                             int* __restrict__ off, int* __restrict__ cursor)
{
    __shared__ int sb[NB_SCAN + 1];
    int tid = threadIdx.x;
    if (tid < 64) {
        int v = (tid < NB_SCAN) ? bsum[tid] : 0;
        int orig = v;
        #pragma unroll
        for (int o = 1; o < 64; o <<= 1) {
            int t = __shfl_up(v, o, 64);
            if (tid >= o) v += t;
        }
        if (tid < NB_SCAN) sb[tid] = v - orig;   // exclusive
        if (tid == 63)     sb[NB_SCAN] = v;      // grand total
    }
    __syncthreads();
    int i = blockIdx.x * blockDim.x + tid;
    if (i < N_NODES) {
        int e = incl[i] - deg[i] + sb[i >> 10];
        off[i] = e;
        cursor[i] = e;
    } else if (i == N_NODES) {
        off[N_NODES] = sb[NB_SCAN];
    }
}

__global__ void scatter_kernel(const int* __restrict__ srcp, const int* __restrict__ dstp,
                               int* __restrict__ cursor, int* __restrict__ esrc)
{
    int e = blockIdx.x * blockDim.x + threadIdx.x;
    if (e >= ET) return;
    int s, dt;
    if (e < N_EDGES) { s = srcp[e]; dt = dstp[e]; }
    else             { s = e - N_EDGES; dt = s; }
    int pos = atomicAdd(cursor + dt, 1);
    esrc[pos] = s;
}

// ===== MFMA dual GEMM: 16 rows x 64 cols per wave, <=128 VGPR, 4 waves/SIMD =========
// xl: 3-term bf16x2 (~fp32); xr: single-term bf16.
__global__ __launch_bounds__(256, 4)
void gemm_mfma_kernel(const unsigned short* __restrict__ hhi,
                      const unsigned short* __restrict__ hlo,
                      const unsigned short* __restrict__ wlh,
                      const unsigned short* __restrict__ wll,
                      const unsigned short* __restrict__ wrh,
                      const float* __restrict__ bl, const float* __restrict__ br,
                      unsigned short* __restrict__ xlb, unsigned short* __restrict__ xrb,
                      int n)
{
    int lane = threadIdx.x & 63;
    int wid  = threadIdx.x >> 6;          // 0..3
    int rowB = blockIdx.x >> 1;           // 64-row strip
    int c0   = (blockIdx.x & 1) * 64;     // column half
    int m0   = rowB * 64 + wid * 16;      // this wave's 16 rows
    if (m0 >= n) return;
    int gl = lane & 15;
    int kg = lane >> 4;

    // bias prologue
    float blc[4], brc[4];
    #pragma unroll
    for (int t = 0; t < 4; t++) {
        blc[t] = bl[c0 + t * 16 + gl];
        brc[t] = br[c0 + t * 16 + gl];
    }

    int ar = m0 + gl; if (ar >= n) ar = n - 1;
    const unsigned short* ah = hhi + (size_t)ar * D + kg * 8;
    const unsigned short* al = hlo + (size_t)ar * D + kg * 8;
    bf16x8 Ah[4], Al[4];
    #pragma unroll
    for (int ks = 0; ks < 4; ks++) {
        Ah[ks] = *(const bf16x8*)(ah + ks * 32);
        Al[ks] = *(const bf16x8*)(al + ks * 32);
    }

    f32x4 accl[4], accr[4];
    #pragma unroll
    for (int t = 0; t < 4; t++) {
        accl[t] = (f32x4){0.f, 0.f, 0.f, 0.f};
        accr[t] = (f32x4){0.f, 0.f, 0.f, 0.f};
    }

    #pragma unroll
    for (int ks = 0; ks < 4; ks++) {
        #pragma unroll
        for (int t = 0; t < 4; t++) {
            size_t boff = (size_t)(c0 + t * 16 + gl) * D + kg * 8 + ks * 32;
            bf16x8 bLH = *(const bf16x8*)(wlh + boff);
            bf16x8 bLL = *(const bf16x8*)(wll + boff);
            bf16x8 bRH = *(const bf16x8*)(wrh + boff);
            accl[t] = __builtin_amdgcn_mfma_f32_16x16x32_bf16(Ah[ks], bLH, accl[t], 0, 0, 0);
            accl[t] = __builtin_amdgcn_mfma_f32_16x16x32_bf16(Al[ks], bLH, accl[t], 0, 0, 0);
            accl[t] = __builtin_amdgcn_mfma_f32_16x16x32_bf16(Ah[ks], bLL, accl[t], 0, 0, 0);
            accr[t] = __builtin_amdgcn_mfma_f32_16x16x32_bf16(Ah[ks], bRH, accr[t], 0, 0, 0);
        }
    }

    // epilogue: C/D layout col = lane&15, row = (lane>>4)*4 + reg
    #pragma unroll
    for (int t = 0; t < 4; t++) {
        int col = c0 + t * 16 + gl;
        #pragma unroll
        for (int r = 0; r < 4; r++) {
            int row = m0 + kg * 4 + r;
            if (row < n) {
                xlb[(size_t)row * D + col] = f2bf_rne(accl[t][r] + blc[t]);
                xrb[(size_t)row * D + col] = f2bf_rne(accr[t][r] + brc[t]);
            }
        }
    }
}

// ===== fused per-node GATv2: 16 lanes/edge, 2 edges/group/iter (8 edges in flight) ===
// defer-max online softmax; LAST=1 fuses log_softmax.
template <int LAST>
__global__ void node_attn_kernel(const unsigned short* __restrict__ xlb,
                                 const unsigned short* __restrict__ xrb,
                                 const float* __restrict__ att,
                                 const float* __restrict__ bias,
                                 const int* __restrict__ off,
                                 const int* __restrict__ esrc,
                                 float* __restrict__ outF,
                                 unsigned short* __restrict__ hhi,
                                 unsigned short* __restrict__ hlo)
{
    int i    = (int)((blockIdx.x * (size_t)blockDim.x + threadIdx.x) >> 6);
    int lane = threadIdx.x & 63;
    if (i >= N_NODES) return;
    int g  = lane >> 4;     // edge-pair slot 0..3
    int gl = lane & 15;     // lane within group
    int fb = gl * 8;        // this lane's 8 features (4 f32x2)

    f32x2 aa[4], rr[4];
    {
        float4 a0 = *(const float4*)(att + fb);
        float4 a1 = *(const float4*)(att + fb + 4);
        aa[0] = (f32x2){a0.x, a0.y}; aa[1] = (f32x2){a0.z, a0.w};
        aa[2] = (f32x2){a1.x, a1.y}; aa[3] = (f32x2){a1.z, a1.w};
        uint4 r4 = *(const uint4*)(xrb + (size_t)i * D + fb);
        rr[0] = unpack_bf2(r4.x); rr[1] = unpack_bf2(r4.y);
        rr[2] = unpack_bf2(r4.z); rr[3] = unpack_bf2(r4.w);
    }

    float m = -1e30f, l = 0.f;
    f32x2 acc[4];
    #pragma unroll
    for (int j = 0; j < 4; j++) acc[j] = (f32x2){0.f, 0.f};

    int k    = off[i];
    int kEnd = off[i + 1];
    int last = kEnd - 1;

    int ka = k + g, kb = k + 4 + g;
    bool va = ka < kEnd, vb = kb < kEnd;
    int sa = esrc[va ? ka : last];
    int sb = esrc[vb ? kb : last];
    uint4 x4a = *(const uint4*)(xlb + (size_t)sa * D + fb);
    uint4 x4b = *(const uint4*)(xlb + (size_t)sb * D + fb);

    while (k < kEnd) {
        int kn = k + 8;
        uint4 nxa = x4a, nxb = x4b;
        bool nva = false, nvb = false;
        if (kn < kEnd) {                       // wave-uniform: prefetch next 8 edges
            int nka = kn + g, nkb = kn + 4 + g;
            nva = nka < kEnd; nvb = nkb < kEnd;
            int nsa = esrc[nva ? nka : last];
            int nsb = esrc[nvb ? nkb : last];
            nxa = *(const uint4*)(xlb + (size_t)nsa * D + fb);
            nxb = *(const uint4*)(xlb + (size_t)nsb * D + fb);
        }
        f32x2 xa[4], xb[4];
        xa[0] = unpack_bf2(x4a.x); xa[1] = unpack_bf2(x4a.y);
        xa[2] = unpack_bf2(x4a.z); xa[3] = unpack_bf2(x4a.w);
        xb[0] = unpack_bf2(x4b.x); xb[1] = unpack_bf2(x4b.y);
        xb[2] = unpack_bf2(x4b.z); xb[3] = unpack_bf2(x4b.w);
        // two packed scores
        f32x2 s2a = {0.f, 0.f}, s2b = {0.f, 0.f};
        #pragma unroll
        for (int j = 0; j < 4; j++) {
            f32x2 va_ = xa[j] + rr[j];
            f32x2 la_ = __builtin_elementwise_max(va_, va_ * SLOPE);
            s2a = s2a + la_ * aa[j];
            f32x2 vb_ = xb[j] + rr[j];
            f32x2 lb_ = __builtin_elementwise_max(vb_, vb_ * SLOPE);
            s2b = s2b + lb_ * aa[j];
        }
        float sca = s2a.x + s2a.y;
        float scb = s2b.x + s2b.y;
        sca += __shfl_xor(sca, 1, 64);
        scb += __shfl_xor(scb, 1, 64);
        sca += __shfl_xor(sca, 2, 64);
        scb += __shfl_xor(scb, 2, 64);
        sca += __shfl_xor(sca, 4, 64);
        scb += __shfl_xor(scb, 4, 64);
        sca += __shfl_xor(sca, 8, 64);
        scb += __shfl_xor(scb, 8, 64);
        float mx2 = fmaxf(sca, scb);
        // shared defer-max update for the pair
        if (__any(mx2 > m + 8.f)) {
            float mn = fmaxf(m, mx2);
            float f  = __expf(m - mn);
            float pa = va ? __expf(sca - mn) : 0.f;
            float pb = vb ? __expf(scb - mn) : 0.f;
            l = l * f + pa + pb;
            f32x2 fv = {f, f}, pav = {pa, pa}, pbv = {pb, pb};
            #pragma unroll
            for (int j = 0; j < 4; j++)
                acc[j] = acc[j] * fv + xa[j] * pav + xb[j] * pbv;
            m = mn;
        } else {
            float pa = va ? __expf(sca - m) : 0.f;
            float pb = vb ? __expf(scb - m) : 0.f;
            l += pa + pb;
            f32x2 pav = {pa, pa}, pbv = {pb, pb};
            #pragma unroll
            for (int j = 0; j < 4; j++)
                acc[j] = acc[j] + xa[j] * pav + xb[j] * pbv;
        }
        x4a = nxa; x4b = nxb; va = nva; vb = nvb;
        k = kn;
    }

    // merge the 4 groups' online-softmax states (xor 16, then 32)
    #pragma unroll
    for (int o = 16; o <= 32; o <<= 1) {
        float mo  = __shfl_xor(m, o, 64);
        float lo2 = __shfl_xor(l, o, 64);
        float mn  = fmaxf(m, mo);
        float f1  = __expf(m - mn);
        float f2s = __expf(mo - mn);
        l = l * f1 + lo2 * f2s;
        f32x2 f1v = {f1, f1}, f2v = {f2s, f2s};
        #pragma unroll
        for (int j = 0; j < 4; j++) {
            f32x2 ao;
            ao.x = __shfl_xor(acc[j].x, o, 64);
            ao.y = __shfl_xor(acc[j].y, o, 64);
            acc[j] = acc[j] * f1v + ao * f2v;
        }
        m = mn;
    }

    float inv = 1.f / (l + 1e-16f);
    f32x2 hv[4];
    {
        float4 b0 = *(const float4*)(bias + fb);
        float4 b1 = *(const float4*)(bias + fb + 4);
        f32x2 iv = {inv, inv}, z = {0.f, 0.f};
        f32x2 bb0 = {b0.x, b0.y}, bb1 = {b0.z, b0.w};
        f32x2 bb2 = {b1.x, b1.y}, bb3 = {b1.z, b1.w};
        hv[0] = __builtin_elementwise_max(acc[0] * iv + bb0, z);
        hv[1] = __builtin_elementwise_max(acc[1] * iv + bb1, z);
        hv[2] = __builtin_elementwise_max(acc[2] * iv + bb2, z);
        hv[3] = __builtin_elementwise_max(acc[3] * iv + bb3, z);
    }

    if (LAST) {
        float mx = fmaxf(hv[0].x, hv[0].y);
        #pragma unroll
        for (int j = 1; j < 4; j++) mx = fmaxf(mx, fmaxf(hv[j].x, hv[j].y));
        mx = fmaxf(mx, __shfl_xor(mx, 1, 64));
        mx = fmaxf(mx, __shfl_xor(mx, 2, 64));
        mx = fmaxf(mx, __shfl_xor(mx, 4, 64));
        mx = fmaxf(mx, __shfl_xor(mx, 8, 64));
        float se = 0.f;
        #pragma unroll
        for (int j = 0; j < 4; j++) se += __expf(hv[j].x - mx) + __expf(hv[j].y - mx);
        se += __shfl_xor(se, 1, 64);
        se += __shfl_xor(se, 2, 64);
        se += __shfl_xor(se, 4, 64);
        se += __shfl_xor(se, 8, 64);
        float ls = logf(se) + mx;
        if (g == 0) {
            float4 o0 = make_float4(hv[0].x - ls, hv[0].y - ls, hv[1].x - ls, hv[1].y - ls);
            float4 o1 = make_float4(hv[2].x - ls, hv[2].y - ls, hv[3].x - ls, hv[3].y - ls);
            float* dst = outF + (size_t)i * D + fb;
            *(float4*)(dst)     = o0;
            *(float4*)(dst + 4) = o1;
        }
    } else {
        if (g < 2) {
            unsigned pk[4];
            #pragma unroll
            for (int j = 0; j < 4; j++) {
                float v0 = hv[j].x, v1 = hv[j].y;
                unsigned short h0 = f2bf_rne(v0), h1 = f2bf_rne(v1);
                if (g == 0) pk[j] = (unsigned)h0 | ((unsigned)h1 << 16);
                else {
                    unsigned short l0 = f2bf_rne(v0 - bf2f(h0));
                    unsigned short l1 = f2bf_rne(v1 - bf2f(h1));
                    pk[j] = (unsigned)l0 | ((unsigned)l1 << 16);
                }
            }
            unsigned short* dst = (g == 0 ? hhi : hlo) + (size_t)i * D + fb;
            *(uint4*)dst = make_uint4(pk[0], pk[1], pk[2], pk[3]);
        }
    }
}

extern "C" void kernel_launch(void* const* d_in, const int* in_sizes, int n_in,
                              void* d_out, int out_size, void* d_ws, size_t ws_size,
                              hipStream_t stream)
{
    const float* x    = (const float*)d_in[0];
    const int*   ei   = (const int*)  d_in[1];
    const float* Wl   = (const float*)d_in[2];
    const float* bl   = (const float*)d_in[3];
    const float* Wr   = (const float*)d_in[4];
    const float* br   = (const float*)d_in[5];
    const float* att  = (const float*)d_in[6];
    const float* bias = (const float*)d_in[7];
    float* out = (float*)d_out;

    const int* srcp = ei;
    const int* dstp = ei + N_EDGES;

    const size_t ND = (size_t)N_NODES * D;
    const size_t WSZ = (size_t)NLAYERS * D * D;
    char* ws = (char*)d_ws;
    unsigned short* xlb = (unsigned short*)ws; ws += ND * sizeof(unsigned short);
    unsigned short* xrb = (unsigned short*)ws; ws += ND * sizeof(unsigned short);
    unsigned short* hhi = (unsigned short*)ws; ws += ND * sizeof(unsigned short);
    unsigned short* hlo = (unsigned short*)ws; ws += ND * sizeof(unsigned short);
    unsigned short* wlh = (unsigned short*)ws; ws += WSZ * sizeof(unsigned short);
    unsigned short* wll = (unsigned short*)ws; ws += WSZ * sizeof(unsigned short);
    unsigned short* wrh = (unsigned short*)ws; ws += WSZ * sizeof(unsigned short);
    int* deg    = (int*)ws;  ws += (size_t)N_NODES * sizeof(int);
    int* incl   = (int*)ws;  ws += (size_t)N_NODES * sizeof(int);
    int* off    = (int*)ws;  ws += (size_t)(N_NODES + 1) * sizeof(int);
    int* cursor = (int*)ws;  ws += (size_t)N_NODES * sizeof(int);
    int* bsum   = (int*)ws;  ws += (size_t)NB_SCAN * sizeof(int);
    int* esrc   = (int*)ws;  ws += (size_t)ET * sizeof(int);

    const int prepGrid  = (int)((ND / 4 + 255) / 256);
    const int edgeGrid  = (ET + 255) / 256;
    const int gemmGrid  = ((N_NODES + 63) / 64) * 2;     // 64-row strips x 2 col halves
    const int nodeGrid  = (N_NODES + 3) / 4;
    const int scan3Grid = (N_NODES + 1 + 255) / 256;

    hipMemsetAsync(deg, 0, (size_t)N_NODES * sizeof(int), stream);
    prep_kernel<<<prepGrid, 256, 0, stream>>>(x, Wl, Wr, dstp,
                                              hhi, hlo, wlh, wll, wrh, deg);

    scan1_kernel<<<NB_SCAN, 1024, 0, stream>>>(deg, incl, bsum);
    scan3_kernel<<<scan3Grid, 256, 0, stream>>>(deg, incl, bsum, off, cursor);
    scatter_kernel<<<edgeGrid, 256, 0, stream>>>(srcp, dstp, cursor, esrc);

    for (int l = 0; l < NLAYERS; l++) {
        size_t wOff = (size_t)l * D * D;
        gemm_mfma_kernel<<<gemmGrid, 256, 0, stream>>>(
            hhi, hlo, wlh + wOff, wll + wOff, wrh + wOff,
            bl + (size_t)l * D, br + (size_t)l * D, xlb, xrb, N_NODES);

        if (l == NLAYERS - 1) {
            node_attn_kernel<1><<<nodeGrid, 256, 0, stream>>>(
                xlb, xrb, att + (size_t)l * D, bias + (size_t)l * D,
                off, esrc, out, nullptr, nullptr);
        } else {
            node_attn_kernel<0><<<nodeGrid, 256, 0, stream>>>(
                xlb, xrb, att + (size_t)l * D, bias + (size_t)l * D,
                off, esrc, nullptr, hhi, hlo);
        }
    }
}

// Round 11
// 381.329 us; speedup vs baseline: 1.0961x; 1.0961x over previous
//
#include <hip/hip_runtime.h>
#include <cstdint>
#include <cstddef>

#define N_NODES 50000
#define N_EDGES 800000
#define ET (N_EDGES + N_NODES)   // edges + self loops
#define D 128
#define NLAYERS 3
#define SLOPE 0.2f
#define NB_SCAN ((N_NODES + 1023) / 1024)   // 49 blocks

typedef __bf16 bf16x8 __attribute__((ext_vector_type(8)));
typedef float  f32x4  __attribute__((ext_vector_type(4)));
typedef float  f32x2  __attribute__((ext_vector_type(2)));

// ---- bf16 split helpers (round-to-nearest-even) ----
__device__ __forceinline__ unsigned short f2bf_rne(float v) {
    unsigned u = __float_as_uint(v);
    u += 0x7fffu + ((u >> 16) & 1u);
    return (unsigned short)(u >> 16);
}
__device__ __forceinline__ float bf2f(unsigned short h) {
    return __uint_as_float(((unsigned)h) << 16);
}
__device__ __forceinline__ f32x2 unpack_bf2(unsigned u) {
    f32x2 r;
    r.x = __uint_as_float(u << 16);
    r.y = __uint_as_float(u & 0xffff0000u);
    return r;
}

// ===== merged prep: split x -> bf16 hi/lo, transpose+split weights, degree count =====
__global__ void prep_kernel(const float* __restrict__ x,
                            const float* __restrict__ Wl,
                            const float* __restrict__ Wr,
                            const int* __restrict__ dstp,
                            unsigned short* __restrict__ hhi,
                            unsigned short* __restrict__ hlo,
                            unsigned short* __restrict__ wlh,
                            unsigned short* __restrict__ wll,
                            unsigned short* __restrict__ wrh,
                            int* __restrict__ deg)
{
    int idx = blockIdx.x * blockDim.x + threadIdx.x;
    if (idx < (N_NODES * D) / 4) {
        float4 v = ((const float4*)x)[idx];
        unsigned short h0 = f2bf_rne(v.x), h1 = f2bf_rne(v.y);
        unsigned short h2 = f2bf_rne(v.z), h3 = f2bf_rne(v.w);
        unsigned short l0 = f2bf_rne(v.x - bf2f(h0)), l1 = f2bf_rne(v.y - bf2f(h1));
        unsigned short l2 = f2bf_rne(v.z - bf2f(h2)), l3 = f2bf_rne(v.w - bf2f(h3));
        uint2 hw, lw;
        hw.x = (unsigned)h0 | ((unsigned)h1 << 16);
        hw.y = (unsigned)h2 | ((unsigned)h3 << 16);
        lw.x = (unsigned)l0 | ((unsigned)l1 << 16);
        lw.y = (unsigned)l2 | ((unsigned)l3 << 16);
        ((uint2*)hhi)[idx] = hw;
        ((uint2*)hlo)[idx] = lw;
    }
    if (idx < NLAYERS * D * D) {
        int l   = idx / (D * D);
        int rem = idx - l * D * D;
        int kk  = rem / D;
        int nn  = rem - kk * D;
        int tp  = l * D * D + nn * D + kk;
        float v = Wl[idx];
        unsigned short h = f2bf_rne(v);
        wlh[tp] = h;
        wll[tp] = f2bf_rne(v - bf2f(h));
        wrh[tp] = f2bf_rne(Wr[idx]);
    }
    if (idx < ET) {
        int dt = (idx < N_EDGES) ? dstp[idx] : idx - N_EDGES;
        atomicAdd(deg + dt, 1);
    }
}

// ================= CSR build ==================
__global__ void scan1_kernel(const int* __restrict__ deg,
                             int* __restrict__ incl, int* __restrict__ bsum)
{
    __shared__ int tmp[1024];
    int tid = threadIdx.x;
    int i = blockIdx.x * 1024 + tid;
    int v = (i < N_NODES) ? deg[i] : 0;
    tmp[tid] = v;
    __syncthreads();
    #pragma unroll
    for (int o = 1; o < 1024; o <<= 1) {
        int t = (tid >= o) ? tmp[tid - o] : 0;
        __syncthreads();
        tmp[tid] += t;
        __syncthreads();
    }
    if (i < N_NODES) incl[i] = tmp[tid];
    if (tid == 1023) bsum[blockIdx.x] = tmp[1023];
}

__global__ void scan3_kernel(const int* __restrict__ deg, const int* __restrict__ incl,
                             const int* __restrict__ bsum,
                             int* __restrict__ off, int* __restrict__ cursor)
{
    __shared__ int sb[NB_SCAN + 1];
    int tid = threadIdx.x;
    if (tid < 64) {
        int v = (tid < NB_SCAN) ? bsum[tid] : 0;
        int orig = v;
        #pragma unroll
        for (int o = 1; o < 64; o <<= 1) {
            int t = __shfl_up(v, o, 64);
            if (tid >= o) v += t;
        }
        if (tid < NB_SCAN) sb[tid] = v - orig;   // exclusive
        if (tid == 63)     sb[NB_SCAN] = v;      // grand total
    }
    __syncthreads();
    int i = blockIdx.x * blockDim.x + tid;
    if (i < N_NODES) {
        int e = incl[i] - deg[i] + sb[i >> 10];
        off[i] = e;
        cursor[i] = e;
    } else if (i == N_NODES) {
        off[N_NODES] = sb[NB_SCAN];
    }
}

__global__ void scatter_kernel(const int* __restrict__ srcp, const int* __restrict__ dstp,
                               int* __restrict__ cursor, int* __restrict__ esrc)
{
    int e = blockIdx.x * blockDim.x + threadIdx.x;
    if (e >= ET) return;
    int s, dt;
    if (e < N_EDGES) { s = srcp[e]; dt = dstp[e]; }
    else             { s = e - N_EDGES; dt = s; }
    int pos = atomicAdd(cursor + dt, 1);
    esrc[pos] = s;
}

// ===== MFMA dual GEMM (R9 geometry: 32 rows x 64 cols/wave, k-chunked) =============
// + fused bs epilogue: bs[row] += 0.6 * dot(att, xl_row)  (f32 atomic, bs pre-zeroed)
__global__ __launch_bounds__(256, 2)
void gemm_mfma_kernel(const unsigned short* __restrict__ hhi,
                      const unsigned short* __restrict__ hlo,
                      const unsigned short* __restrict__ wlh,
                      const unsigned short* __restrict__ wll,
                      const unsigned short* __restrict__ wrh,
                      const float* __restrict__ bl, const float* __restrict__ br,
                      const float* __restrict__ att,
                      unsigned short* __restrict__ xlb, unsigned short* __restrict__ xrb,
                      float* __restrict__ bs, int n)
{
    int lane = threadIdx.x & 63;
    int wid  = threadIdx.x >> 6;          // 0..3
    int rowB = blockIdx.x >> 1;
    int c0   = (blockIdx.x & 1) * 64;     // column half
    int m0   = (rowB * 4 + wid) * 32;     // this wave's 32 rows
    if (m0 >= n) return;
    int gl = lane & 15;
    int kg = lane >> 4;

    // prologue loads (bias + att columns)
    float blc[4], brc[4], attc[4];
    #pragma unroll
    for (int t = 0; t < 4; t++) {
        blc[t]  = bl [c0 + t * 16 + gl];
        brc[t]  = br [c0 + t * 16 + gl];
        attc[t] = att[c0 + t * 16 + gl];
    }

    int ar0 = m0 + gl;      if (ar0 >= n) ar0 = n - 1;
    int ar1 = m0 + 16 + gl; if (ar1 >= n) ar1 = n - 1;
    const unsigned short* ah0 = hhi + (size_t)ar0 * D + kg * 8;
    const unsigned short* al0 = hlo + (size_t)ar0 * D + kg * 8;
    const unsigned short* ah1 = hhi + (size_t)ar1 * D + kg * 8;
    const unsigned short* al1 = hlo + (size_t)ar1 * D + kg * 8;

    f32x4 accl[2][4], accr[2][4];
    #pragma unroll
    for (int rt = 0; rt < 2; rt++)
        #pragma unroll
        for (int t = 0; t < 4; t++) {
            accl[rt][t] = (f32x4){0.f, 0.f, 0.f, 0.f};
            accr[rt][t] = (f32x4){0.f, 0.f, 0.f, 0.f};
        }

    #pragma unroll
    for (int ks = 0; ks < 4; ks++) {
        bf16x8 aH0 = *(const bf16x8*)(ah0 + ks * 32);
        bf16x8 aL0 = *(const bf16x8*)(al0 + ks * 32);
        bf16x8 aH1 = *(const bf16x8*)(ah1 + ks * 32);
        bf16x8 aL1 = *(const bf16x8*)(al1 + ks * 32);
        #pragma unroll
        for (int t = 0; t < 4; t++) {
            size_t boff = (size_t)(c0 + t * 16 + gl) * D + kg * 8 + ks * 32;
            bf16x8 bLH = *(const bf16x8*)(wlh + boff);
            bf16x8 bLL = *(const bf16x8*)(wll + boff);
            bf16x8 bRH = *(const bf16x8*)(wrh + boff);
            accl[0][t] = __builtin_amdgcn_mfma_f32_16x16x32_bf16(aH0, bLH, accl[0][t], 0, 0, 0);
            accl[0][t] = __builtin_amdgcn_mfma_f32_16x16x32_bf16(aL0, bLH, accl[0][t], 0, 0, 0);
            accl[0][t] = __builtin_amdgcn_mfma_f32_16x16x32_bf16(aH0, bLL, accl[0][t], 0, 0, 0);
            accr[0][t] = __builtin_amdgcn_mfma_f32_16x16x32_bf16(aH0, bRH, accr[0][t], 0, 0, 0);
            accl[1][t] = __builtin_amdgcn_mfma_f32_16x16x32_bf16(aH1, bLH, accl[1][t], 0, 0, 0);
            accl[1][t] = __builtin_amdgcn_mfma_f32_16x16x32_bf16(aL1, bLH, accl[1][t], 0, 0, 0);
            accl[1][t] = __builtin_amdgcn_mfma_f32_16x16x32_bf16(aH1, bLL, accl[1][t], 0, 0, 0);
            accr[1][t] = __builtin_amdgcn_mfma_f32_16x16x32_bf16(aH1, bRH, accr[1][t], 0, 0, 0);
        }
    }

    // epilogue: stores + fused bs partial (C/D layout: col = lane&15, row = (lane>>4)*4+reg)
    #pragma unroll
    for (int rt = 0; rt < 2; rt++) {
        #pragma unroll
        for (int r = 0; r < 4; r++) {
            int row = m0 + rt * 16 + kg * 4 + r;
            if (row < n) {
                float p = 0.f;
                #pragma unroll
                for (int t = 0; t < 4; t++) {
                    int col = c0 + t * 16 + gl;
                    float vl = accl[rt][t][r] + blc[t];
                    xlb[(size_t)row * D + col] = f2bf_rne(vl);
                    xrb[(size_t)row * D + col] = f2bf_rne(accr[rt][t][r] + brc[t]);
                    p = fmaf(attc[t], vl, p);
                }
                // reduce p over the 16-lane gl group (lanes share kg)
                p += __shfl_xor(p, 1, 64);
                p += __shfl_xor(p, 2, 64);
                p += __shfl_xor(p, 4, 64);
                p += __shfl_xor(p, 8, 64);
                if (gl == 0) unsafeAtomicAdd(bs + row, 0.6f * p);
            }
        }
    }
}

// ===== fused per-node GATv2: 16 lanes/edge, 2 edges/group/iter =======================
// score = bs[s] + bd + 0.4 * sum(att * |xl_s + xr_d|)   [leaky = 0.6v + 0.4|v|, exact]
// defer-max online softmax; LAST=1 fuses log_softmax.
template <int LAST>
__global__ void node_attn_kernel(const unsigned short* __restrict__ xlb,
                                 const unsigned short* __restrict__ xrb,
                                 const float* __restrict__ bs,
                                 const float* __restrict__ att,
                                 const float* __restrict__ bias,
                                 const int* __restrict__ off,
                                 const int* __restrict__ esrc,
                                 float* __restrict__ outF,
                                 unsigned short* __restrict__ hhi,
                                 unsigned short* __restrict__ hlo)
{
    int i    = (int)((blockIdx.x * (size_t)blockDim.x + threadIdx.x) >> 6);
    int lane = threadIdx.x & 63;
    if (i >= N_NODES) return;
    int g  = lane >> 4;     // edge-pair slot 0..3
    int gl = lane & 15;     // lane within group
    int fb = gl * 8;        // this lane's 8 features

    float aav[8], rrv[8];
    {
        float4 a0 = *(const float4*)(att + fb);
        float4 a1 = *(const float4*)(att + fb + 4);
        aav[0] = a0.x; aav[1] = a0.y; aav[2] = a0.z; aav[3] = a0.w;
        aav[4] = a1.x; aav[5] = a1.y; aav[6] = a1.z; aav[7] = a1.w;
        uint4 r4 = *(const uint4*)(xrb + (size_t)i * D + fb);
        f32x2 q;
        q = unpack_bf2(r4.x); rrv[0] = q.x; rrv[1] = q.y;
        q = unpack_bf2(r4.y); rrv[2] = q.x; rrv[3] = q.y;
        q = unpack_bf2(r4.z); rrv[4] = q.x; rrv[5] = q.y;
        q = unpack_bf2(r4.w); rrv[6] = q.x; rrv[7] = q.y;
    }
    // bd = 0.6 * dot(att, xr_i)  (per node, once)
    float bd;
    {
        float pd = 0.f;
        #pragma unroll
        for (int j = 0; j < 8; j++) pd = fmaf(aav[j], rrv[j], pd);
        pd += __shfl_xor(pd, 1, 64);
        pd += __shfl_xor(pd, 2, 64);
        pd += __shfl_xor(pd, 4, 64);
        pd += __shfl_xor(pd, 8, 64);
        bd = 0.6f * pd;
    }

    float m = -1e30f, l = 0.f;
    float acc[8];
    #pragma unroll
    for (int j = 0; j < 8; j++) acc[j] = 0.f;

    int k    = off[i];
    int kEnd = off[i + 1];
    int last = kEnd - 1;

    int ka = k + g, kb = k + 4 + g;
    bool va = ka < kEnd, vb = kb < kEnd;
    int sa = esrc[va ? ka : last];
    int sb = esrc[vb ? kb : last];
    uint4 x4a = *(const uint4*)(xlb + (size_t)sa * D + fb);
    uint4 x4b = *(const uint4*)(xlb + (size_t)sb * D + fb);
    float bsa = bs[sa], bsb = bs[sb];

    while (k < kEnd) {
        int kn = k + 8;
        uint4 nxa = x4a, nxb = x4b;
        float nbsa = bsa, nbsb = bsb;
        bool nva = false, nvb = false;
        if (kn < kEnd) {                       // wave-uniform: prefetch next 8 edges
            int nka = kn + g, nkb = kn + 4 + g;
            nva = nka < kEnd; nvb = nkb < kEnd;
            int nsa = esrc[nva ? nka : last];
            int nsb = esrc[nvb ? nkb : last];
            nxa = *(const uint4*)(xlb + (size_t)nsa * D + fb);
            nxb = *(const uint4*)(xlb + (size_t)nsb * D + fb);
            nbsa = bs[nsa]; nbsb = bs[nsb];
        }
        float xa[8], xb[8];
        {
            f32x2 q;
            q = unpack_bf2(x4a.x); xa[0] = q.x; xa[1] = q.y;
            q = unpack_bf2(x4a.y); xa[2] = q.x; xa[3] = q.y;
            q = unpack_bf2(x4a.z); xa[4] = q.x; xa[5] = q.y;
            q = unpack_bf2(x4a.w); xa[6] = q.x; xa[7] = q.y;
            q = unpack_bf2(x4b.x); xb[0] = q.x; xb[1] = q.y;
            q = unpack_bf2(x4b.y); xb[2] = q.x; xb[3] = q.y;
            q = unpack_bf2(x4b.z); xb[4] = q.x; xb[5] = q.y;
            q = unpack_bf2(x4b.w); xb[6] = q.x; xb[7] = q.y;
        }
        // S2 = sum(att * |x + r|)   (abs is a free VOP3 modifier)
        float s2a = 0.f, s2b = 0.f;
        #pragma unroll
        for (int j = 0; j < 8; j++) {
            s2a = fmaf(aav[j], fabsf(xa[j] + rrv[j]), s2a);
            s2b = fmaf(aav[j], fabsf(xb[j] + rrv[j]), s2b);
        }
        s2a += __shfl_xor(s2a, 1, 64);
        s2b += __shfl_xor(s2b, 1, 64);
        s2a += __shfl_xor(s2a, 2, 64);
        s2b += __shfl_xor(s2b, 2, 64);
        s2a += __shfl_xor(s2a, 4, 64);
        s2b += __shfl_xor(s2b, 4, 64);
        s2a += __shfl_xor(s2a, 8, 64);
        s2b += __shfl_xor(s2b, 8, 64);
        float sca = bsa + bd + 0.4f * s2a;
        float scb = bsb + bd + 0.4f * s2b;
        float mx2 = fmaxf(sca, scb);
        if (__any(mx2 > m + 8.f)) {
            float mn = fmaxf(m, mx2);
            float f  = __expf(m - mn);
            float pa = va ? __expf(sca - mn) : 0.f;
            float pb = vb ? __expf(scb - mn) : 0.f;
            l = l * f + pa + pb;
            #pragma unroll
            for (int j = 0; j < 8; j++)
                acc[j] = fmaf(acc[j], f, fmaf(xa[j], pa, xb[j] * pb));
            m = mn;
        } else {
            float pa = va ? __expf(sca - m) : 0.f;
            float pb = vb ? __expf(scb - m) : 0.f;
            l += pa + pb;
            #pragma unroll
            for (int j = 0; j < 8; j++)
                acc[j] = fmaf(xa[j], pa, fmaf(xb[j], pb, acc[j]));
        }
        x4a = nxa; x4b = nxb; bsa = nbsa; bsb = nbsb; va = nva; vb = nvb;
        k = kn;
    }

    // merge the 4 groups' online-softmax states (xor 16, then 32)
    #pragma unroll
    for (int o = 16; o <= 32; o <<= 1) {
        float mo  = __shfl_xor(m, o, 64);
        float lo2 = __shfl_xor(l, o, 64);
        float mn  = fmaxf(m, mo);
        float f1  = __expf(m - mn);
        float f2s = __expf(mo - mn);
        l = l * f1 + lo2 * f2s;
        #pragma unroll
        for (int j = 0; j < 8; j++) {
            float ao = __shfl_xor(acc[j], o, 64);
            acc[j] = acc[j] * f1 + ao * f2s;
        }
        m = mn;
    }

    float inv = 1.f / (l + 1e-16f);
    float hv[8];
    {
        float4 b0 = *(const float4*)(bias + fb);
        float4 b1 = *(const float4*)(bias + fb + 4);
        float bb[8] = {b0.x, b0.y, b0.z, b0.w, b1.x, b1.y, b1.z, b1.w};
        #pragma unroll
        for (int j = 0; j < 8; j++) hv[j] = fmaxf(fmaf(acc[j], inv, bb[j]), 0.f);
    }

    if (LAST) {
        float mx = hv[0];
        #pragma unroll
        for (int j = 1; j < 8; j++) mx = fmaxf(mx, hv[j]);
        mx = fmaxf(mx, __shfl_xor(mx, 1, 64));
        mx = fmaxf(mx, __shfl_xor(mx, 2, 64));
        mx = fmaxf(mx, __shfl_xor(mx, 4, 64));
        mx = fmaxf(mx, __shfl_xor(mx, 8, 64));
        float se = 0.f;
        #pragma unroll
        for (int j = 0; j < 8; j++) se += __expf(hv[j] - mx);
        se += __shfl_xor(se, 1, 64);
        se += __shfl_xor(se, 2, 64);
        se += __shfl_xor(se, 4, 64);
        se += __shfl_xor(se, 8, 64);
        float ls = logf(se) + mx;
        if (g == 0) {
            float4 o0 = make_float4(hv[0] - ls, hv[1] - ls, hv[2] - ls, hv[3] - ls);
            float4 o1 = make_float4(hv[4] - ls, hv[5] - ls, hv[6] - ls, hv[7] - ls);
            float* dst = outF + (size_t)i * D + fb;
            *(float4*)(dst)     = o0;
            *(float4*)(dst + 4) = o1;
        }
    } else {
        if (g < 2) {
            unsigned pk[4];
            #pragma unroll
            for (int j = 0; j < 4; j++) {
                float v0 = hv[j * 2], v1 = hv[j * 2 + 1];
                unsigned short h0 = f2bf_rne(v0), h1 = f2bf_rne(v1);
                if (g == 0) pk[j] = (unsigned)h0 | ((unsigned)h1 << 16);
                else {
                    unsigned short l0 = f2bf_rne(v0 - bf2f(h0));
                    unsigned short l1 = f2bf_rne(v1 - bf2f(h1));
                    pk[j] = (unsigned)l0 | ((unsigned)l1 << 16);
                }
            }
            unsigned short* dst = (g == 0 ? hhi : hlo) + (size_t)i * D + fb;
            *(uint4*)dst = make_uint4(pk[0], pk[1], pk[2], pk[3]);
        }
    }
}

extern "C" void kernel_launch(void* const* d_in, const int* in_sizes, int n_in,
                              void* d_out, int out_size, void* d_ws, size_t ws_size,
                              hipStream_t stream)
{
    const float* x    = (const float*)d_in[0];
    const int*   ei   = (const int*)  d_in[1];
    const float* Wl   = (const float*)d_in[2];
    const float* bl   = (const float*)d_in[3];
    const float* Wr   = (const float*)d_in[4];
    const float* br   = (const float*)d_in[5];
    const float* att  = (const float*)d_in[6];
    const float* bias = (const float*)d_in[7];
    float* out = (float*)d_out;

    const int* srcp = ei;
    const int* dstp = ei + N_EDGES;

    const size_t ND = (size_t)N_NODES * D;
    const size_t WSZ = (size_t)NLAYERS * D * D;
    char* ws = (char*)d_ws;
    unsigned short* xlb = (unsigned short*)ws; ws += ND * sizeof(unsigned short);
    unsigned short* xrb = (unsigned short*)ws; ws += ND * sizeof(unsigned short);
    unsigned short* hhi = (unsigned short*)ws; ws += ND * sizeof(unsigned short);
    unsigned short* hlo = (unsigned short*)ws; ws += ND * sizeof(unsigned short);
    unsigned short* wlh = (unsigned short*)ws; ws += WSZ * sizeof(unsigned short);
    unsigned short* wll = (unsigned short*)ws; ws += WSZ * sizeof(unsigned short);
    unsigned short* wrh = (unsigned short*)ws; ws += WSZ * sizeof(unsigned short);
    float* bs   = (float*)ws; ws += (size_t)N_NODES * sizeof(float);
    int* deg    = (int*)ws;  ws += (size_t)N_NODES * sizeof(int);
    int* incl   = (int*)ws;  ws += (size_t)N_NODES * sizeof(int);
    int* off    = (int*)ws;  ws += (size_t)(N_NODES + 1) * sizeof(int);
    int* cursor = (int*)ws;  ws += (size_t)N_NODES * sizeof(int);
    int* bsum   = (int*)ws;  ws += (size_t)NB_SCAN * sizeof(int);
    int* esrc   = (int*)ws;  ws += (size_t)ET * sizeof(int);

    const int prepGrid  = (int)((ND / 4 + 255) / 256);
    const int edgeGrid  = (ET + 255) / 256;
    const int gemmGrid  = ((N_NODES + 127) / 128) * 2;   // 128-row blocks x 2 col halves
    const int nodeGrid  = (N_NODES + 3) / 4;
    const int scan3Grid = (N_NODES + 1 + 255) / 256;

    hipMemsetAsync(deg, 0, (size_t)N_NODES * sizeof(int), stream);
    prep_kernel<<<prepGrid, 256, 0, stream>>>(x, Wl, Wr, dstp,
                                              hhi, hlo, wlh, wll, wrh, deg);

    scan1_kernel<<<NB_SCAN, 1024, 0, stream>>>(deg, incl, bsum);
    scan3_kernel<<<scan3Grid, 256, 0, stream>>>(deg, incl, bsum, off, cursor);
    scatter_kernel<<<edgeGrid, 256, 0, stream>>>(srcp, dstp, cursor, esrc);

    for (int l = 0; l < NLAYERS; l++) {
        size_t wOff = (size_t)l * D * D;
        hipMemsetAsync(bs, 0, (size_t)N_NODES * sizeof(float), stream);
        gemm_mfma_kernel<<<gemmGrid, 256, 0, stream>>>(
            hhi, hlo, wlh + wOff, wll + wOff, wrh + wOff,
            bl + (size_t)l * D, br + (size_t)l * D, att + (size_t)l * D,
            xlb, xrb, bs, N_NODES);

        if (l == NLAYERS - 1) {
            node_attn_kernel<1><<<nodeGrid, 256, 0, stream>>>(
                xlb, xrb, bs, att + (size_t)l * D, bias + (size_t)l * D,
                off, esrc, out, nullptr, nullptr);
        } else {
            node_attn_kernel<0><<<nodeGrid, 256, 0, stream>>>(
                xlb, xrb, bs, att + (size_t)l * D, bias + (size_t)l * D,
                off, esrc, nullptr, hhi, hlo);
        }
    }
}

// Round 12
// 338.737 us; speedup vs baseline: 1.2339x; 1.1257x over previous
//
#include <hip/hip_runtime.h>
#include <cstdint>
#include <cstddef>

#define N_NODES 50000
#define N_EDGES 800000
#define ET (N_EDGES + N_NODES)   // edges + self loops
#define D 128
#define NLAYERS 3
#define SLOPE 0.2f
#define NB_SCAN ((N_NODES + 1023) / 1024)   // 49 blocks
#define GEMM_BLOCKS (((N_NODES + 127) / 128) * 2)   // 782
#define EDGE_BLOCKS ((ET + 255) / 256)              // 3321

typedef __bf16 bf16x8 __attribute__((ext_vector_type(8)));
typedef float  f32x4  __attribute__((ext_vector_type(4)));
typedef float  f32x2  __attribute__((ext_vector_type(2)));

// ---- bf16 split helpers (round-to-nearest-even) ----
__device__ __forceinline__ unsigned short f2bf_rne(float v) {
    unsigned u = __float_as_uint(v);
    u += 0x7fffu + ((u >> 16) & 1u);
    return (unsigned short)(u >> 16);
}
__device__ __forceinline__ float bf2f(unsigned short h) {
    return __uint_as_float(((unsigned)h) << 16);
}
__device__ __forceinline__ f32x2 unpack_bf2(unsigned u) {
    f32x2 r;
    r.x = __uint_as_float(u << 16);
    r.y = __uint_as_float(u & 0xffff0000u);
    return r;
}

// ===== merged prep: split x -> bf16 hi/lo, transpose+split weights, degree count =====
__global__ void prep_kernel(const float* __restrict__ x,
                            const float* __restrict__ Wl,
                            const float* __restrict__ Wr,
                            const int* __restrict__ dstp,
                            unsigned short* __restrict__ hhi,
                            unsigned short* __restrict__ hlo,
                            unsigned short* __restrict__ wlh,
                            unsigned short* __restrict__ wll,
                            unsigned short* __restrict__ wrh,
                            int* __restrict__ deg)
{
    int idx = blockIdx.x * blockDim.x + threadIdx.x;
    if (idx < (N_NODES * D) / 4) {
        float4 v = ((const float4*)x)[idx];
        unsigned short h0 = f2bf_rne(v.x), h1 = f2bf_rne(v.y);
        unsigned short h2 = f2bf_rne(v.z), h3 = f2bf_rne(v.w);
        unsigned short l0 = f2bf_rne(v.x - bf2f(h0)), l1 = f2bf_rne(v.y - bf2f(h1));
        unsigned short l2 = f2bf_rne(v.z - bf2f(h2)), l3 = f2bf_rne(v.w - bf2f(h3));
        uint2 hw, lw;
        hw.x = (unsigned)h0 | ((unsigned)h1 << 16);
        hw.y = (unsigned)h2 | ((unsigned)h3 << 16);
        lw.x = (unsigned)l0 | ((unsigned)l1 << 16);
        lw.y = (unsigned)l2 | ((unsigned)l3 << 16);
        ((uint2*)hhi)[idx] = hw;
        ((uint2*)hlo)[idx] = lw;
    }
    if (idx < NLAYERS * D * D) {
        int l   = idx / (D * D);
        int rem = idx - l * D * D;
        int kk  = rem / D;
        int nn  = rem - kk * D;
        int tp  = l * D * D + nn * D + kk;
        float v = Wl[idx];
        unsigned short h = f2bf_rne(v);
        wlh[tp] = h;
        wll[tp] = f2bf_rne(v - bf2f(h));
        wrh[tp] = f2bf_rne(Wr[idx]);
    }
    if (idx < ET) {
        int dt = (idx < N_EDGES) ? dstp[idx] : idx - N_EDGES;
        atomicAdd(deg + dt, 1);
    }
}

// ================= CSR build ==================
__global__ void scan1_kernel(const int* __restrict__ deg,
                             int* __restrict__ incl, int* __restrict__ bsum)
{
    __shared__ int tmp[1024];
    int tid = threadIdx.x;
    int i = blockIdx.x * 1024 + tid;
    int v = (i < N_NODES) ? deg[i] : 0;
    tmp[tid] = v;
    __syncthreads();
    #pragma unroll
    for (int o = 1; o < 1024; o <<= 1) {
        int t = (tid >= o) ? tmp[tid - o] : 0;
        __syncthreads();
        tmp[tid] += t;
        __syncthreads();
    }
    if (i < N_NODES) incl[i] = tmp[tid];
    if (tid == 1023) bsum[blockIdx.x] = tmp[1023];
}

__global__ void scan3_kernel(const int* __restrict__ deg, const int* __restrict__ incl,
                             const int* __restrict__ bsum,
                             int* __restrict__ off, int* __restrict__ cursor)
{
    __shared__ int sb[NB_SCAN + 1];
    int tid = threadIdx.x;
    if (tid < 64) {
        int v = (tid < NB_SCAN) ? bsum[tid] : 0;
        int orig = v;
        #pragma unroll
        for (int o = 1; o < 64; o <<= 1) {
            int t = __shfl_up(v, o, 64);
            if (tid >= o) v += t;
        }
        if (tid < NB_SCAN) sb[tid] = v - orig;   // exclusive
        if (tid == 63)     sb[NB_SCAN] = v;      // grand total
    }
    __syncthreads();
    int i = blockIdx.x * blockDim.x + tid;
    if (i < N_NODES) {
        int e = incl[i] - deg[i] + sb[i >> 10];
        off[i] = e;
        cursor[i] = e;
    } else if (i == N_NODES) {
        off[N_NODES] = sb[NB_SCAN];
    }
}

// ===== MFMA dual GEMM (32 rows x 64 cols/wave) + optional fused CSR scatter ==========
// Blocks [0, GEMM_BLOCKS): gemm; blocks [GEMM_BLOCKS, +EDGE_BLOCKS): edge scatter.
// The scatter is latency-bound with no resource appetite -> hides under gemm.
// bs[row] += 0.6 * dot(att, xl_row) fused in the gemm epilogue (bs pre-zeroed).
template <bool WITH_SCATTER>
__global__ __launch_bounds__(256, 2)
void gemm_mfma_kernel(const unsigned short* __restrict__ hhi,
                      const unsigned short* __restrict__ hlo,
                      const unsigned short* __restrict__ wlh,
                      const unsigned short* __restrict__ wll,
                      const unsigned short* __restrict__ wrh,
                      const float* __restrict__ bl, const float* __restrict__ br,
                      const float* __restrict__ att,
                      unsigned short* __restrict__ xlb, unsigned short* __restrict__ xrb,
                      float* __restrict__ bs,
                      const int* __restrict__ srcp, const int* __restrict__ dstp,
                      int* __restrict__ cursor, int* __restrict__ esrc, int n)
{
    if (WITH_SCATTER && blockIdx.x >= GEMM_BLOCKS) {
        int e = (blockIdx.x - GEMM_BLOCKS) * 256 + threadIdx.x;
        if (e < ET) {
            int s, dt;
            if (e < N_EDGES) { s = srcp[e]; dt = dstp[e]; }
            else             { s = e - N_EDGES; dt = s; }
            int pos = atomicAdd(cursor + dt, 1);
            esrc[pos] = s;
        }
        return;
    }

    int lane = threadIdx.x & 63;
    int wid  = threadIdx.x >> 6;          // 0..3
    int rowB = blockIdx.x >> 1;
    int c0   = (blockIdx.x & 1) * 64;     // column half
    int m0   = (rowB * 4 + wid) * 32;     // this wave's 32 rows
    if (m0 >= n) return;
    int gl = lane & 15;
    int kg = lane >> 4;

    float blc[4], brc[4], attc[4];
    #pragma unroll
    for (int t = 0; t < 4; t++) {
        blc[t]  = bl [c0 + t * 16 + gl];
        brc[t]  = br [c0 + t * 16 + gl];
        attc[t] = att[c0 + t * 16 + gl];
    }

    int ar0 = m0 + gl;      if (ar0 >= n) ar0 = n - 1;
    int ar1 = m0 + 16 + gl; if (ar1 >= n) ar1 = n - 1;
    const unsigned short* ah0 = hhi + (size_t)ar0 * D + kg * 8;
    const unsigned short* al0 = hlo + (size_t)ar0 * D + kg * 8;
    const unsigned short* ah1 = hhi + (size_t)ar1 * D + kg * 8;
    const unsigned short* al1 = hlo + (size_t)ar1 * D + kg * 8;

    f32x4 accl[2][4], accr[2][4];
    #pragma unroll
    for (int rt = 0; rt < 2; rt++)
        #pragma unroll
        for (int t = 0; t < 4; t++) {
            accl[rt][t] = (f32x4){0.f, 0.f, 0.f, 0.f};
            accr[rt][t] = (f32x4){0.f, 0.f, 0.f, 0.f};
        }

    #pragma unroll
    for (int ks = 0; ks < 4; ks++) {
        bf16x8 aH0 = *(const bf16x8*)(ah0 + ks * 32);
        bf16x8 aL0 = *(const bf16x8*)(al0 + ks * 32);
        bf16x8 aH1 = *(const bf16x8*)(ah1 + ks * 32);
        bf16x8 aL1 = *(const bf16x8*)(al1 + ks * 32);
        #pragma unroll
        for (int t = 0; t < 4; t++) {
            size_t boff = (size_t)(c0 + t * 16 + gl) * D + kg * 8 + ks * 32;
            bf16x8 bLH = *(const bf16x8*)(wlh + boff);
            bf16x8 bLL = *(const bf16x8*)(wll + boff);
            bf16x8 bRH = *(const bf16x8*)(wrh + boff);
            accl[0][t] = __builtin_amdgcn_mfma_f32_16x16x32_bf16(aH0, bLH, accl[0][t], 0, 0, 0);
            accl[0][t] = __builtin_amdgcn_mfma_f32_16x16x32_bf16(aL0, bLH, accl[0][t], 0, 0, 0);
            accl[0][t] = __builtin_amdgcn_mfma_f32_16x16x32_bf16(aH0, bLL, accl[0][t], 0, 0, 0);
            accr[0][t] = __builtin_amdgcn_mfma_f32_16x16x32_bf16(aH0, bRH, accr[0][t], 0, 0, 0);
            accl[1][t] = __builtin_amdgcn_mfma_f32_16x16x32_bf16(aH1, bLH, accl[1][t], 0, 0, 0);
            accl[1][t] = __builtin_amdgcn_mfma_f32_16x16x32_bf16(aL1, bLH, accl[1][t], 0, 0, 0);
            accl[1][t] = __builtin_amdgcn_mfma_f32_16x16x32_bf16(aH1, bLL, accl[1][t], 0, 0, 0);
            accr[1][t] = __builtin_amdgcn_mfma_f32_16x16x32_bf16(aH1, bRH, accr[1][t], 0, 0, 0);
        }
    }

    #pragma unroll
    for (int rt = 0; rt < 2; rt++) {
        #pragma unroll
        for (int r = 0; r < 4; r++) {
            int row = m0 + rt * 16 + kg * 4 + r;
            if (row < n) {
                float p = 0.f;
                #pragma unroll
                for (int t = 0; t < 4; t++) {
                    int col = c0 + t * 16 + gl;
                    float vl = accl[rt][t][r] + blc[t];
                    xlb[(size_t)row * D + col] = f2bf_rne(vl);
                    xrb[(size_t)row * D + col] = f2bf_rne(accr[rt][t][r] + brc[t]);
                    p = fmaf(attc[t], vl, p);
                }
                p += __shfl_xor(p, 1, 64);
                p += __shfl_xor(p, 2, 64);
                p += __shfl_xor(p, 4, 64);
                p += __shfl_xor(p, 8, 64);
                if (gl == 0) unsafeAtomicAdd(bs + row, 0.6f * p);
            }
        }
    }
}

// ===== fused per-node GATv2: 16 lanes/edge, 2 edges/group/iter =======================
// score' = bs[s] + 0.4*sum(att*|xl_s+xr_d|)   [bd term dropped: segment-constant, exact]
// 0.4 folded into aav. defer-max online softmax; LAST=1 fuses log_softmax.
template <int LAST>
__global__ void node_attn_kernel(const unsigned short* __restrict__ xlb,
                                 const unsigned short* __restrict__ xrb,
                                 const float* __restrict__ bs,
                                 const float* __restrict__ att,
                                 const float* __restrict__ bias,
                                 const int* __restrict__ off,
                                 const int* __restrict__ esrc,
                                 float* __restrict__ outF,
                                 unsigned short* __restrict__ hhi,
                                 unsigned short* __restrict__ hlo)
{
    int i    = (int)((blockIdx.x * (size_t)blockDim.x + threadIdx.x) >> 6);
    int lane = threadIdx.x & 63;
    if (i >= N_NODES) return;
    int g  = lane >> 4;     // edge-pair slot 0..3
    int gl = lane & 15;     // lane within group
    int fb = gl * 8;        // this lane's 8 features

    float aav[8], rrv[8];
    {
        float4 a0 = *(const float4*)(att + fb);
        float4 a1 = *(const float4*)(att + fb + 4);
        aav[0] = 0.4f * a0.x; aav[1] = 0.4f * a0.y; aav[2] = 0.4f * a0.z; aav[3] = 0.4f * a0.w;
        aav[4] = 0.4f * a1.x; aav[5] = 0.4f * a1.y; aav[6] = 0.4f * a1.z; aav[7] = 0.4f * a1.w;
        uint4 r4 = *(const uint4*)(xrb + (size_t)i * D + fb);
        f32x2 q;
        q = unpack_bf2(r4.x); rrv[0] = q.x; rrv[1] = q.y;
        q = unpack_bf2(r4.y); rrv[2] = q.x; rrv[3] = q.y;
        q = unpack_bf2(r4.z); rrv[4] = q.x; rrv[5] = q.y;
        q = unpack_bf2(r4.w); rrv[6] = q.x; rrv[7] = q.y;
    }

    float m = -1e30f, l = 0.f;
    float acc[8];
    #pragma unroll
    for (int j = 0; j < 8; j++) acc[j] = 0.f;

    int k    = off[i];
    int kEnd = off[i + 1];
    int last = kEnd - 1;

    int ka = k + g, kb = k + 4 + g;
    bool va = ka < kEnd, vb = kb < kEnd;
    int sa = esrc[va ? ka : last];
    int sb = esrc[vb ? kb : last];
    uint4 x4a = *(const uint4*)(xlb + (size_t)sa * D + fb);
    uint4 x4b = *(const uint4*)(xlb + (size_t)sb * D + fb);
    float bsa = bs[sa], bsb = bs[sb];

    while (k < kEnd) {
        int kn = k + 8;
        uint4 nxa = x4a, nxb = x4b;
        float nbsa = bsa, nbsb = bsb;
        bool nva = false, nvb = false;
        if (kn < kEnd) {                       // wave-uniform: prefetch next 8 edges
            int nka = kn + g, nkb = kn + 4 + g;
            nva = nka < kEnd; nvb = nkb < kEnd;
            int nsa = esrc[nva ? nka : last];
            int nsb = esrc[nvb ? nkb : last];
            nxa = *(const uint4*)(xlb + (size_t)nsa * D + fb);
            nxb = *(const uint4*)(xlb + (size_t)nsb * D + fb);
            nbsa = bs[nsa]; nbsb = bs[nsb];
        }
        float xa[8], xb[8];
        {
            f32x2 q;
            q = unpack_bf2(x4a.x); xa[0] = q.x; xa[1] = q.y;
            q = unpack_bf2(x4a.y); xa[2] = q.x; xa[3] = q.y;
            q = unpack_bf2(x4a.z); xa[4] = q.x; xa[5] = q.y;
            q = unpack_bf2(x4a.w); xa[6] = q.x; xa[7] = q.y;
            q = unpack_bf2(x4b.x); xb[0] = q.x; xb[1] = q.y;
            q = unpack_bf2(x4b.y); xb[2] = q.x; xb[3] = q.y;
            q = unpack_bf2(x4b.z); xb[4] = q.x; xb[5] = q.y;
            q = unpack_bf2(x4b.w); xb[6] = q.x; xb[7] = q.y;
        }
        float s2a = 0.f, s2b = 0.f;
        #pragma unroll
        for (int j = 0; j < 8; j++) {
            s2a = fmaf(aav[j], fabsf(xa[j] + rrv[j]), s2a);
            s2b = fmaf(aav[j], fabsf(xb[j] + rrv[j]), s2b);
        }
        s2a += __shfl_xor(s2a, 1, 64);
        s2b += __shfl_xor(s2b, 1, 64);
        s2a += __shfl_xor(s2a, 2, 64);
        s2b += __shfl_xor(s2b, 2, 64);
        s2a += __shfl_xor(s2a, 4, 64);
        s2b += __shfl_xor(s2b, 4, 64);
        s2a += __shfl_xor(s2a, 8, 64);
        s2b += __shfl_xor(s2b, 8, 64);
        float sca = bsa + s2a;
        float scb = bsb + s2b;
        float mx2 = fmaxf(sca, scb);
        if (__any(mx2 > m + 8.f)) {
            float mn = fmaxf(m, mx2);
            float f  = __expf(m - mn);
            float pa = va ? __expf(sca - mn) : 0.f;
            float pb = vb ? __expf(scb - mn) : 0.f;
            l = l * f + pa + pb;
            #pragma unroll
            for (int j = 0; j < 8; j++)
                acc[j] = fmaf(acc[j], f, fmaf(xa[j], pa, xb[j] * pb));
            m = mn;
        } else {
            float pa = va ? __expf(sca - m) : 0.f;
            float pb = vb ? __expf(scb - m) : 0.f;
            l += pa + pb;
            #pragma unroll
            for (int j = 0; j < 8; j++)
                acc[j] = fmaf(xa[j], pa, fmaf(xb[j], pb, acc[j]));
        }
        x4a = nxa; x4b = nxb; bsa = nbsa; bsb = nbsb; va = nva; vb = nvb;
        k = kn;
    }

    // merge the 4 groups' online-softmax states (xor 16, then 32)
    #pragma unroll
    for (int o = 16; o <= 32; o <<= 1) {
        float mo  = __shfl_xor(m, o, 64);
        float lo2 = __shfl_xor(l, o, 64);
        float mn  = fmaxf(m, mo);
        float f1  = __expf(m - mn);
        float f2s = __expf(mo - mn);
        l = l * f1 + lo2 * f2s;
        #pragma unroll
        for (int j = 0; j < 8; j++) {
            float ao = __shfl_xor(acc[j], o, 64);
            acc[j] = acc[j] * f1 + ao * f2s;
        }
        m = mn;
    }

    float inv = 1.f / (l + 1e-16f);
    float hv[8];
    {
        float4 b0 = *(const float4*)(bias + fb);
        float4 b1 = *(const float4*)(bias + fb + 4);
        float bb[8] = {b0.x, b0.y, b0.z, b0.w, b1.x, b1.y, b1.z, b1.w};
        #pragma unroll
        for (int j = 0; j < 8; j++) hv[j] = fmaxf(fmaf(acc[j], inv, bb[j]), 0.f);
    }

    if (LAST) {
        float mx = hv[0];
        #pragma unroll
        for (int j = 1; j < 8; j++) mx = fmaxf(mx, hv[j]);
        mx = fmaxf(mx, __shfl_xor(mx, 1, 64));
        mx = fmaxf(mx, __shfl_xor(mx, 2, 64));
        mx = fmaxf(mx, __shfl_xor(mx, 4, 64));
        mx = fmaxf(mx, __shfl_xor(mx, 8, 64));
        float se = 0.f;
        #pragma unroll
        for (int j = 0; j < 8; j++) se += __expf(hv[j] - mx);
        se += __shfl_xor(se, 1, 64);
        se += __shfl_xor(se, 2, 64);
        se += __shfl_xor(se, 4, 64);
        se += __shfl_xor(se, 8, 64);
        float ls = logf(se) + mx;
        if (g == 0) {
            float4 o0 = make_float4(hv[0] - ls, hv[1] - ls, hv[2] - ls, hv[3] - ls);
            float4 o1 = make_float4(hv[4] - ls, hv[5] - ls, hv[6] - ls, hv[7] - ls);
            float* dst = outF + (size_t)i * D + fb;
            *(float4*)(dst)     = o0;
            *(float4*)(dst + 4) = o1;
        }
    } else {
        if (g < 2) {
            unsigned pk[4];
            #pragma unroll
            for (int j = 0; j < 4; j++) {
                float v0 = hv[j * 2], v1 = hv[j * 2 + 1];
                unsigned short h0 = f2bf_rne(v0), h1 = f2bf_rne(v1);
                if (g == 0) pk[j] = (unsigned)h0 | ((unsigned)h1 << 16);
                else {
                    unsigned short l0 = f2bf_rne(v0 - bf2f(h0));
                    unsigned short l1 = f2bf_rne(v1 - bf2f(h1));
                    pk[j] = (unsigned)l0 | ((unsigned)l1 << 16);
                }
            }
            unsigned short* dst = (g == 0 ? hhi : hlo) + (size_t)i * D + fb;
            *(uint4*)dst = make_uint4(pk[0], pk[1], pk[2], pk[3]);
        }
    }
}

extern "C" void kernel_launch(void* const* d_in, const int* in_sizes, int n_in,
                              void* d_out, int out_size, void* d_ws, size_t ws_size,
                              hipStream_t stream)
{
    const float* x    = (const float*)d_in[0];
    const int*   ei   = (const int*)  d_in[1];
    const float* Wl   = (const float*)d_in[2];
    const float* bl   = (const float*)d_in[3];
    const float* Wr   = (const float*)d_in[4];
    const float* br   = (const float*)d_in[5];
    const float* att  = (const float*)d_in[6];
    const float* bias = (const float*)d_in[7];
    float* out = (float*)d_out;

    const int* srcp = ei;
    const int* dstp = ei + N_EDGES;

    const size_t ND = (size_t)N_NODES * D;
    const size_t WSZ = (size_t)NLAYERS * D * D;
    char* ws = (char*)d_ws;
    unsigned short* xlb = (unsigned short*)ws; ws += ND * sizeof(unsigned short);
    unsigned short* xrb = (unsigned short*)ws; ws += ND * sizeof(unsigned short);
    unsigned short* hhi = (unsigned short*)ws; ws += ND * sizeof(unsigned short);
    unsigned short* hlo = (unsigned short*)ws; ws += ND * sizeof(unsigned short);
    unsigned short* wlh = (unsigned short*)ws; ws += WSZ * sizeof(unsigned short);
    unsigned short* wll = (unsigned short*)ws; ws += WSZ * sizeof(unsigned short);
    unsigned short* wrh = (unsigned short*)ws; ws += WSZ * sizeof(unsigned short);
    float* bs   = (float*)ws; ws += (size_t)N_NODES * sizeof(float);
    int* deg    = (int*)ws;  ws += (size_t)N_NODES * sizeof(int);
    int* incl   = (int*)ws;  ws += (size_t)N_NODES * sizeof(int);
    int* off    = (int*)ws;  ws += (size_t)(N_NODES + 1) * sizeof(int);
    int* cursor = (int*)ws;  ws += (size_t)N_NODES * sizeof(int);
    int* bsum   = (int*)ws;  ws += (size_t)NB_SCAN * sizeof(int);
    int* esrc   = (int*)ws;  ws += (size_t)ET * sizeof(int);

    const int prepGrid  = (int)((ND / 4 + 255) / 256);
    const int nodeGrid  = (N_NODES + 3) / 4;
    const int scan3Grid = (N_NODES + 1 + 255) / 256;

    hipMemsetAsync(deg, 0, (size_t)N_NODES * sizeof(int), stream);
    prep_kernel<<<prepGrid, 256, 0, stream>>>(x, Wl, Wr, dstp,
                                              hhi, hlo, wlh, wll, wrh, deg);

    scan1_kernel<<<NB_SCAN, 1024, 0, stream>>>(deg, incl, bsum);
    scan3_kernel<<<scan3Grid, 256, 0, stream>>>(deg, incl, bsum, off, cursor);

    for (int l = 0; l < NLAYERS; l++) {
        size_t wOff = (size_t)l * D * D;
        hipMemsetAsync(bs, 0, (size_t)N_NODES * sizeof(float), stream);
        if (l == 0) {
            // gemm + CSR scatter fused: scatter blocks hide under gemm latency
            gemm_mfma_kernel<true><<<GEMM_BLOCKS + EDGE_BLOCKS, 256, 0, stream>>>(
                hhi, hlo, wlh + wOff, wll + wOff, wrh + wOff,
                bl + (size_t)l * D, br + (size_t)l * D, att + (size_t)l * D,
                xlb, xrb, bs, srcp, dstp, cursor, esrc, N_NODES);
        } else {
            gemm_mfma_kernel<false><<<GEMM_BLOCKS, 256, 0, stream>>>(
                hhi, hlo, wlh + wOff, wll + wOff, wrh + wOff,
                bl + (size_t)l * D, br + (size_t)l * D, att + (size_t)l * D,
                xlb, xrb, bs, nullptr, nullptr, nullptr, nullptr, N_NODES);
        }

        if (l == NLAYERS - 1) {
            node_attn_kernel<1><<<nodeGrid, 256, 0, stream>>>(
                xlb, xrb, bs, att + (size_t)l * D, bias + (size_t)l * D,
                off, esrc, out, nullptr, nullptr);
        } else {
            node_attn_kernel<0><<<nodeGrid, 256, 0, stream>>>(
                xlb, xrb, bs, att + (size_t)l * D, bias + (size_t)l * D,
                off, esrc, nullptr, hhi, hlo);
        }
    }
}

// Round 13
// 332.493 us; speedup vs baseline: 1.2571x; 1.0188x over previous
//
#include <hip/hip_runtime.h>
#include <cstdint>
#include <cstddef>

#define N_NODES 50000
#define N_EDGES 800000
#define ET (N_EDGES + N_NODES)   // edges + self loops
#define D 128
#define NLAYERS 3
#define SLOPE 0.2f
#define LOG2E 1.44269504f
#define DEFER_THR 11.5415603f    // 8 nats in log2 units
#define NB_SCAN ((N_NODES + 1023) / 1024)   // 49 blocks
#define GEMM_BLOCKS (((N_NODES + 127) / 128) * 2)   // 782
#define EDGE_BLOCKS ((ET + 255) / 256)              // 3321

typedef __bf16 bf16x8 __attribute__((ext_vector_type(8)));
typedef float  f32x4  __attribute__((ext_vector_type(4)));
typedef float  f32x2  __attribute__((ext_vector_type(2)));

__device__ __forceinline__ unsigned short f2bf_rne(float v) {
    unsigned u = __float_as_uint(v);
    u += 0x7fffu + ((u >> 16) & 1u);
    return (unsigned short)(u >> 16);
}
__device__ __forceinline__ f32x2 unpack_bf2(unsigned u) {
    f32x2 r;
    r.x = __uint_as_float(u << 16);
    r.y = __uint_as_float(u & 0xffff0000u);
    return r;
}

// ===== merged prep: x -> bf16, transpose weights -> bf16, degree count ==============
__global__ void prep_kernel(const float* __restrict__ x,
                            const float* __restrict__ Wl,
                            const float* __restrict__ Wr,
                            const int* __restrict__ dstp,
                            unsigned short* __restrict__ hhi,
                            unsigned short* __restrict__ wlh,
                            unsigned short* __restrict__ wrh,
                            int* __restrict__ deg)
{
    int idx = blockIdx.x * blockDim.x + threadIdx.x;
    if (idx < (N_NODES * D) / 4) {
        float4 v = ((const float4*)x)[idx];
        uint2 hw;
        hw.x = (unsigned)f2bf_rne(v.x) | ((unsigned)f2bf_rne(v.y) << 16);
        hw.y = (unsigned)f2bf_rne(v.z) | ((unsigned)f2bf_rne(v.w) << 16);
        ((uint2*)hhi)[idx] = hw;
    }
    if (idx < NLAYERS * D * D) {
        int l   = idx / (D * D);
        int rem = idx - l * D * D;
        int kk  = rem / D;
        int nn  = rem - kk * D;
        int tp  = l * D * D + nn * D + kk;
        wlh[tp] = f2bf_rne(Wl[idx]);
        wrh[tp] = f2bf_rne(Wr[idx]);
    }
    if (idx < ET) {
        int dt = (idx < N_EDGES) ? dstp[idx] : idx - N_EDGES;
        atomicAdd(deg + dt, 1);
    }
}

// ================= CSR build ==================
__global__ void scan1_kernel(const int* __restrict__ deg,
                             int* __restrict__ incl, int* __restrict__ bsum)
{
    __shared__ int tmp[1024];
    int tid = threadIdx.x;
    int i = blockIdx.x * 1024 + tid;
    int v = (i < N_NODES) ? deg[i] : 0;
    tmp[tid] = v;
    __syncthreads();
    #pragma unroll
    for (int o = 1; o < 1024; o <<= 1) {
        int t = (tid >= o) ? tmp[tid - o] : 0;
        __syncthreads();
        tmp[tid] += t;
        __syncthreads();
    }
    if (i < N_NODES) incl[i] = tmp[tid];
    if (tid == 1023) bsum[blockIdx.x] = tmp[1023];
}

__global__ void scan3_kernel(const int* __restrict__ deg, const int* __restrict__ incl,
                             const int* __restrict__ bsum,
                             int* __restrict__ off, int* __restrict__ cursor,
                             int* __restrict__ esrc)
{
    __shared__ int sb[NB_SCAN + 1];
    int tid = threadIdx.x;
    if (tid < 64) {
        int v = (tid < NB_SCAN) ? bsum[tid] : 0;
        int orig = v;
        #pragma unroll
        for (int o = 1; o < 64; o <<= 1) {
            int t = __shfl_up(v, o, 64);
            if (tid >= o) v += t;
        }
        if (tid < NB_SCAN) sb[tid] = v - orig;   // exclusive
        if (tid == 63)     sb[NB_SCAN] = v;      // grand total
    }
    __syncthreads();
    if (blockIdx.x == 0 && tid < 16) esrc[ET + tid] = 0;   // pad (safe over-reads)
    int i = blockIdx.x * blockDim.x + tid;
    if (i < N_NODES) {
        int e = incl[i] - deg[i] + sb[i >> 10];
        off[i] = e;
        cursor[i] = e;
    } else if (i == N_NODES) {
        off[N_NODES] = sb[NB_SCAN];
    }
}

// ===== MFMA dual GEMM, 1-term bf16 (32 rows x 64 cols/wave) + optional CSR scatter ===
// bs2[row] = {half0, half1}: each col-half block plain-stores its slot (no atomics,
// no memset). Value = 0.6*LOG2E*dot(att, xl_row_half)  (exp2-rebased score part).
template <bool WITH_SCATTER>
__global__ __launch_bounds__(256, 2)
void gemm_mfma_kernel(const unsigned short* __restrict__ hhi,
                      const unsigned short* __restrict__ wlh,
                      const unsigned short* __restrict__ wrh,
                      const float* __restrict__ bl, const float* __restrict__ br,
                      const float* __restrict__ att,
                      unsigned short* __restrict__ xlb, unsigned short* __restrict__ xrb,
                      float* __restrict__ bs2,
                      const int* __restrict__ srcp, const int* __restrict__ dstp,
                      int* __restrict__ cursor, int* __restrict__ esrc, int n)
{
    if (WITH_SCATTER && blockIdx.x >= GEMM_BLOCKS) {
        int e = (blockIdx.x - GEMM_BLOCKS) * 256 + threadIdx.x;
        if (e < ET) {
            int s, dt;
            if (e < N_EDGES) { s = srcp[e]; dt = dstp[e]; }
            else             { s = e - N_EDGES; dt = s; }
            int pos = atomicAdd(cursor + dt, 1);
            esrc[pos] = s;
        }
        return;
    }

    int lane = threadIdx.x & 63;
    int wid  = threadIdx.x >> 6;          // 0..3
    int rowB = blockIdx.x >> 1;
    int half = blockIdx.x & 1;
    int c0   = half * 64;                 // column half
    int m0   = (rowB * 4 + wid) * 32;     // this wave's 32 rows
    if (m0 >= n) return;
    int gl = lane & 15;
    int kg = lane >> 4;

    float blc[4], brc[4], attc[4];
    #pragma unroll
    for (int t = 0; t < 4; t++) {
        blc[t]  = bl [c0 + t * 16 + gl];
        brc[t]  = br [c0 + t * 16 + gl];
        attc[t] = att[c0 + t * 16 + gl];
    }

    int ar0 = m0 + gl;      if (ar0 >= n) ar0 = n - 1;
    int ar1 = m0 + 16 + gl; if (ar1 >= n) ar1 = n - 1;
    const unsigned short* ah0 = hhi + (size_t)ar0 * D + kg * 8;
    const unsigned short* ah1 = hhi + (size_t)ar1 * D + kg * 8;

    bf16x8 Ah0[4], Ah1[4];
    #pragma unroll
    for (int ks = 0; ks < 4; ks++) {
        Ah0[ks] = *(const bf16x8*)(ah0 + ks * 32);
        Ah1[ks] = *(const bf16x8*)(ah1 + ks * 32);
    }

    f32x4 accl[2][4], accr[2][4];
    #pragma unroll
    for (int rt = 0; rt < 2; rt++)
        #pragma unroll
        for (int t = 0; t < 4; t++) {
            accl[rt][t] = (f32x4){0.f, 0.f, 0.f, 0.f};
            accr[rt][t] = (f32x4){0.f, 0.f, 0.f, 0.f};
        }

    #pragma unroll
    for (int ks = 0; ks < 4; ks++) {
        #pragma unroll
        for (int t = 0; t < 4; t++) {
            size_t boff = (size_t)(c0 + t * 16 + gl) * D + kg * 8 + ks * 32;
            bf16x8 bLH = *(const bf16x8*)(wlh + boff);
            bf16x8 bRH = *(const bf16x8*)(wrh + boff);
            accl[0][t] = __builtin_amdgcn_mfma_f32_16x16x32_bf16(Ah0[ks], bLH, accl[0][t], 0, 0, 0);
            accr[0][t] = __builtin_amdgcn_mfma_f32_16x16x32_bf16(Ah0[ks], bRH, accr[0][t], 0, 0, 0);
            accl[1][t] = __builtin_amdgcn_mfma_f32_16x16x32_bf16(Ah1[ks], bLH, accl[1][t], 0, 0, 0);
            accr[1][t] = __builtin_amdgcn_mfma_f32_16x16x32_bf16(Ah1[ks], bRH, accr[1][t], 0, 0, 0);
        }
    }

    // epilogue (C/D: col = lane&15, row = (lane>>4)*4 + reg) + bs half store
    #pragma unroll
    for (int rt = 0; rt < 2; rt++) {
        #pragma unroll
        for (int r = 0; r < 4; r++) {
            int row = m0 + rt * 16 + kg * 4 + r;
            if (row < n) {
                float p = 0.f;
                #pragma unroll
                for (int t = 0; t < 4; t++) {
                    int col = c0 + t * 16 + gl;
                    float vl = accl[rt][t][r] + blc[t];
                    xlb[(size_t)row * D + col] = f2bf_rne(vl);
                    xrb[(size_t)row * D + col] = f2bf_rne(accr[rt][t][r] + brc[t]);
                    p = fmaf(attc[t], vl, p);
                }
                p += __shfl_xor(p, 1, 64);
                p += __shfl_xor(p, 2, 64);
                p += __shfl_xor(p, 4, 64);
                p += __shfl_xor(p, 8, 64);
                if (gl == 0) bs2[row * 2 + half] = 0.6f * LOG2E * p;
            }
        }
    }
}

// ===== fused per-node GATv2: 16 lanes/edge, 2 edges/group/iter, exp2-rebased =========
// score = bs2[s].x + bs2[s].y + sum(aav*|xl_s+xr_d|),  aav pre-scaled by 0.4*LOG2E.
// defer-max online softmax in log2 units; LAST=1 fuses log_softmax.
template <int LAST>
__global__ void node_attn_kernel(const unsigned short* __restrict__ xlb,
                                 const unsigned short* __restrict__ xrb,
                                 const float* __restrict__ bs2,
                                 const float* __restrict__ att,
                                 const float* __restrict__ bias,
                                 const int* __restrict__ off,
                                 const int* __restrict__ esrc,
                                 float* __restrict__ outF,
                                 unsigned short* __restrict__ hhi)
{
    int i    = (int)((blockIdx.x * (size_t)blockDim.x + threadIdx.x) >> 6);
    int lane = threadIdx.x & 63;
    if (i >= N_NODES) return;
    int g  = lane >> 4;     // edge-pair slot 0..3
    int gl = lane & 15;     // lane within group
    int fb = gl * 8;        // this lane's 8 features

    float aav[8], rrv[8];
    {
        float4 a0 = *(const float4*)(att + fb);
        float4 a1 = *(const float4*)(att + fb + 4);
        const float s = 0.4f * LOG2E;
        aav[0] = s * a0.x; aav[1] = s * a0.y; aav[2] = s * a0.z; aav[3] = s * a0.w;
        aav[4] = s * a1.x; aav[5] = s * a1.y; aav[6] = s * a1.z; aav[7] = s * a1.w;
        uint4 r4 = *(const uint4*)(xrb + (size_t)i * D + fb);
        f32x2 q;
        q = unpack_bf2(r4.x); rrv[0] = q.x; rrv[1] = q.y;
        q = unpack_bf2(r4.y); rrv[2] = q.x; rrv[3] = q.y;
        q = unpack_bf2(r4.z); rrv[4] = q.x; rrv[5] = q.y;
        q = unpack_bf2(r4.w); rrv[6] = q.x; rrv[7] = q.y;
    }

    float m = -1e30f, l = 0.f;
    float acc[8];
    #pragma unroll
    for (int j = 0; j < 8; j++) acc[j] = 0.f;

    int k    = off[i];
    int kEnd = off[i + 1];

    int ka = k + g, kb = k + 4 + g;
    bool va = ka < kEnd, vb = kb < kEnd;
    int sa = esrc[ka];                      // esrc padded: over-read is safe
    int sb = esrc[kb];
    uint4 x4a = *(const uint4*)(xlb + (size_t)sa * D + fb);
    uint4 x4b = *(const uint4*)(xlb + (size_t)sb * D + fb);
    float2 ba2 = *(const float2*)(bs2 + sa * 2);
    float2 bb2 = *(const float2*)(bs2 + sb * 2);
    float bsa = ba2.x + ba2.y, bsb = bb2.x + bb2.y;

    while (k < kEnd) {
        int kn = k + 8;
        uint4 nxa = x4a, nxb = x4b;
        float nbsa = bsa, nbsb = bsb;
        bool nva = false, nvb = false;
        if (kn < kEnd) {                    // wave-uniform prefetch
            int nka = kn + g, nkb = kn + 4 + g;
            nva = nka < kEnd; nvb = nkb < kEnd;
            int nsa = esrc[nka];
            int nsb = esrc[nkb];
            nxa = *(const uint4*)(xlb + (size_t)nsa * D + fb);
            nxb = *(const uint4*)(xlb + (size_t)nsb * D + fb);
            float2 na2 = *(const float2*)(bs2 + nsa * 2);
            float2 nb2 = *(const float2*)(bs2 + nsb * 2);
            nbsa = na2.x + na2.y; nbsb = nb2.x + nb2.y;
        }
        float xa[8], xb[8];
        {
            f32x2 q;
            q = unpack_bf2(x4a.x); xa[0] = q.x; xa[1] = q.y;
            q = unpack_bf2(x4a.y); xa[2] = q.x; xa[3] = q.y;
            q = unpack_bf2(x4a.z); xa[4] = q.x; xa[5] = q.y;
            q = unpack_bf2(x4a.w); xa[6] = q.x; xa[7] = q.y;
            q = unpack_bf2(x4b.x); xb[0] = q.x; xb[1] = q.y;
            q = unpack_bf2(x4b.y); xb[2] = q.x; xb[3] = q.y;
            q = unpack_bf2(x4b.z); xb[4] = q.x; xb[5] = q.y;
            q = unpack_bf2(x4b.w); xb[6] = q.x; xb[7] = q.y;
        }
        float s2a = 0.f, s2b = 0.f;
        #pragma unroll
        for (int j = 0; j < 8; j++) {
            s2a = fmaf(aav[j], fabsf(xa[j] + rrv[j]), s2a);
            s2b = fmaf(aav[j], fabsf(xb[j] + rrv[j]), s2b);
        }
        s2a += __shfl_xor(s2a, 1, 64);
        s2b += __shfl_xor(s2b, 1, 64);
        s2a += __shfl_xor(s2a, 2, 64);
        s2b += __shfl_xor(s2b, 2, 64);
        s2a += __shfl_xor(s2a, 4, 64);
        s2b += __shfl_xor(s2b, 4, 64);
        s2a += __shfl_xor(s2a, 8, 64);
        s2b += __shfl_xor(s2b, 8, 64);
        float sca = bsa + s2a;
        float scb = bsb + s2b;
        float mx2 = fmaxf(sca, scb);
        if (__any(mx2 > m + DEFER_THR)) {
            float mn = fmaxf(m, mx2);
            float f  = exp2f(m - mn);
            float pa = va ? exp2f(sca - mn) : 0.f;
            float pb = vb ? exp2f(scb - mn) : 0.f;
            l = l * f + pa + pb;
            #pragma unroll
            for (int j = 0; j < 8; j++)
                acc[j] = fmaf(acc[j], f, fmaf(xa[j], pa, xb[j] * pb));
            m = mn;
        } else {
            float pa = va ? exp2f(sca - m) : 0.f;
            float pb = vb ? exp2f(scb - m) : 0.f;
            l += pa + pb;
            #pragma unroll
            for (int j = 0; j < 8; j++)
                acc[j] = fmaf(xa[j], pa, fmaf(xb[j], pb, acc[j]));
        }
        x4a = nxa; x4b = nxb; bsa = nbsa; bsb = nbsb; va = nva; vb = nvb;
        k = kn;
    }

    // merge the 4 groups' online-softmax states (xor 16, then 32), log2 units
    #pragma unroll
    for (int o = 16; o <= 32; o <<= 1) {
        float mo  = __shfl_xor(m, o, 64);
        float lo2 = __shfl_xor(l, o, 64);
        float mn  = fmaxf(m, mo);
        float f1  = exp2f(m - mn);
        float f2s = exp2f(mo - mn);
        l = l * f1 + lo2 * f2s;
        #pragma unroll
        for (int j = 0; j < 8; j++) {
            float ao = __shfl_xor(acc[j], o, 64);
            acc[j] = acc[j] * f1 + ao * f2s;
        }
        m = mn;
    }

    float inv = 1.f / (l + 1e-16f);
    float hv[8];
    {
        float4 b0 = *(const float4*)(bias + fb);
        float4 b1 = *(const float4*)(bias + fb + 4);
        float bb[8] = {b0.x, b0.y, b0.z, b0.w, b1.x, b1.y, b1.z, b1.w};
        #pragma unroll
        for (int j = 0; j < 8; j++) hv[j] = fmaxf(fmaf(acc[j], inv, bb[j]), 0.f);
    }

    if (LAST) {
        float mx = hv[0];
        #pragma unroll
        for (int j = 1; j < 8; j++) mx = fmaxf(mx, hv[j]);
        mx = fmaxf(mx, __shfl_xor(mx, 1, 64));
        mx = fmaxf(mx, __shfl_xor(mx, 2, 64));
        mx = fmaxf(mx, __shfl_xor(mx, 4, 64));
        mx = fmaxf(mx, __shfl_xor(mx, 8, 64));
        float se = 0.f;
        #pragma unroll
        for (int j = 0; j < 8; j++) se += __expf(hv[j] - mx);
        se += __shfl_xor(se, 1, 64);
        se += __shfl_xor(se, 2, 64);
        se += __shfl_xor(se, 4, 64);
        se += __shfl_xor(se, 8, 64);
        float ls = logf(se) + mx;
        if (g == 0) {
            float4 o0 = make_float4(hv[0] - ls, hv[1] - ls, hv[2] - ls, hv[3] - ls);
            float4 o1 = make_float4(hv[4] - ls, hv[5] - ls, hv[6] - ls, hv[7] - ls);
            float* dst = outF + (size_t)i * D + fb;
            *(float4*)(dst)     = o0;
            *(float4*)(dst + 4) = o1;
        }
    } else {
        if (g == 0) {
            unsigned pk[4];
            #pragma unroll
            for (int j = 0; j < 4; j++) {
                pk[j] = (unsigned)f2bf_rne(hv[j * 2]) |
                        ((unsigned)f2bf_rne(hv[j * 2 + 1]) << 16);
            }
            unsigned short* dst = hhi + (size_t)i * D + fb;
            *(uint4*)dst = make_uint4(pk[0], pk[1], pk[2], pk[3]);
        }
    }
}

extern "C" void kernel_launch(void* const* d_in, const int* in_sizes, int n_in,
                              void* d_out, int out_size, void* d_ws, size_t ws_size,
                              hipStream_t stream)
{
    const float* x    = (const float*)d_in[0];
    const int*   ei   = (const int*)  d_in[1];
    const float* Wl   = (const float*)d_in[2];
    const float* bl   = (const float*)d_in[3];
    const float* Wr   = (const float*)d_in[4];
    const float* br   = (const float*)d_in[5];
    const float* att  = (const float*)d_in[6];
    const float* bias = (const float*)d_in[7];
    float* out = (float*)d_out;

    const int* srcp = ei;
    const int* dstp = ei + N_EDGES;

    const size_t ND = (size_t)N_NODES * D;
    const size_t WSZ = (size_t)NLAYERS * D * D;
    char* ws = (char*)d_ws;
    unsigned short* xlb = (unsigned short*)ws; ws += ND * sizeof(unsigned short);
    unsigned short* xrb = (unsigned short*)ws; ws += ND * sizeof(unsigned short);
    unsigned short* hhi = (unsigned short*)ws; ws += ND * sizeof(unsigned short);
    unsigned short* wlh = (unsigned short*)ws; ws += WSZ * sizeof(unsigned short);
    unsigned short* wrh = (unsigned short*)ws; ws += WSZ * sizeof(unsigned short);
    float* bs2  = (float*)ws; ws += (size_t)N_NODES * 2 * sizeof(float);
    int* deg    = (int*)ws;  ws += (size_t)N_NODES * sizeof(int);
    int* incl   = (int*)ws;  ws += (size_t)N_NODES * sizeof(int);
    int* off    = (int*)ws;  ws += (size_t)(N_NODES + 1) * sizeof(int);
    int* cursor = (int*)ws;  ws += (size_t)N_NODES * sizeof(int);
    int* bsum   = (int*)ws;  ws += (size_t)NB_SCAN * sizeof(int);
    int* esrc   = (int*)ws;  ws += ((size_t)ET + 16) * sizeof(int);

    const int prepGrid  = (int)((ND / 4 + 255) / 256);
    const int nodeGrid  = (N_NODES + 3) / 4;
    const int scan3Grid = (N_NODES + 1 + 255) / 256;

    hipMemsetAsync(deg, 0, (size_t)N_NODES * sizeof(int), stream);
    prep_kernel<<<prepGrid, 256, 0, stream>>>(x, Wl, Wr, dstp, hhi, wlh, wrh, deg);

    scan1_kernel<<<NB_SCAN, 1024, 0, stream>>>(deg, incl, bsum);
    scan3_kernel<<<scan3Grid, 256, 0, stream>>>(deg, incl, bsum, off, cursor, esrc);

    for (int l = 0; l < NLAYERS; l++) {
        size_t wOff = (size_t)l * D * D;
        if (l == 0) {
            gemm_mfma_kernel<true><<<GEMM_BLOCKS + EDGE_BLOCKS, 256, 0, stream>>>(
                hhi, wlh + wOff, wrh + wOff,
                bl + (size_t)l * D, br + (size_t)l * D, att + (size_t)l * D,
                xlb, xrb, bs2, srcp, dstp, cursor, esrc, N_NODES);
        } else {
            gemm_mfma_kernel<false><<<GEMM_BLOCKS, 256, 0, stream>>>(
                hhi, wlh + wOff, wrh + wOff,
                bl + (size_t)l * D, br + (size_t)l * D, att + (size_t)l * D,
                xlb, xrb, bs2, nullptr, nullptr, nullptr, nullptr, N_NODES);
        }

        if (l == NLAYERS - 1) {
            node_attn_kernel<1><<<nodeGrid, 256, 0, stream>>>(
                xlb, xrb, bs2, att + (size_t)l * D, bias + (size_t)l * D,
                off, esrc, out, nullptr);
        } else {
            node_attn_kernel<0><<<nodeGrid, 256, 0, stream>>>(
                xlb, xrb, bs2, att + (size_t)l * D, bias + (size_t)l * D,
                off, esrc, nullptr, hhi);
        }
    }
}

// Round 14
// 326.805 us; speedup vs baseline: 1.2790x; 1.0174x over previous
//
#include <hip/hip_runtime.h>
#include <cstdint>
#include <cstddef>

#define N_NODES 50000
#define N_EDGES 800000
#define ET (N_EDGES + N_NODES)   // edges + self loops
#define D 128
#define NLAYERS 3
#define SLOPE 0.2f
#define LOG2E 1.44269504f
#define DEFER_THR 11.5415603f    // 8 nats in log2 units
#define NB_SCAN ((N_NODES + 1023) / 1024)   // 49 blocks
#define GEMM_BLOCKS (((N_NODES + 127) / 128) * 2)   // 782
#define EDGE_BLOCKS ((ET + 255) / 256)              // 3321

typedef __bf16 bf16x8 __attribute__((ext_vector_type(8)));
typedef float  f32x4  __attribute__((ext_vector_type(4)));
typedef float  f32x2  __attribute__((ext_vector_type(2)));

__device__ __forceinline__ unsigned short f2bf_rne(float v) {
    unsigned u = __float_as_uint(v);
    u += 0x7fffu + ((u >> 16) & 1u);
    return (unsigned short)(u >> 16);
}
__device__ __forceinline__ f32x2 unpack_bf2(unsigned u) {
    f32x2 r;
    r.x = __uint_as_float(u << 16);
    r.y = __uint_as_float(u & 0xffff0000u);
    return r;
}

// ===== merged prep: x -> bf16, transpose weights -> bf16, degree count ==============
__global__ void prep_kernel(const float* __restrict__ x,
                            const float* __restrict__ Wl,
                            const float* __restrict__ Wr,
                            const int* __restrict__ dstp,
                            unsigned short* __restrict__ hhi,
                            unsigned short* __restrict__ wlh,
                            unsigned short* __restrict__ wrh,
                            int* __restrict__ deg)
{
    int idx = blockIdx.x * blockDim.x + threadIdx.x;
    if (idx < (N_NODES * D) / 4) {
        float4 v = ((const float4*)x)[idx];
        uint2 hw;
        hw.x = (unsigned)f2bf_rne(v.x) | ((unsigned)f2bf_rne(v.y) << 16);
        hw.y = (unsigned)f2bf_rne(v.z) | ((unsigned)f2bf_rne(v.w) << 16);
        ((uint2*)hhi)[idx] = hw;
    }
    if (idx < NLAYERS * D * D) {
        int l   = idx / (D * D);
        int rem = idx - l * D * D;
        int kk  = rem / D;
        int nn  = rem - kk * D;
        int tp  = l * D * D + nn * D + kk;
        wlh[tp] = f2bf_rne(Wl[idx]);
        wrh[tp] = f2bf_rne(Wr[idx]);
    }
    if (idx < ET) {
        int dt = (idx < N_EDGES) ? dstp[idx] : idx - N_EDGES;
        atomicAdd(deg + dt, 1);
    }
}

// ================= CSR build ==================
__global__ void scan1_kernel(const int* __restrict__ deg,
                             int* __restrict__ incl, int* __restrict__ bsum)
{
    __shared__ int tmp[1024];
    int tid = threadIdx.x;
    int i = blockIdx.x * 1024 + tid;
    int v = (i < N_NODES) ? deg[i] : 0;
    tmp[tid] = v;
    __syncthreads();
    #pragma unroll
    for (int o = 1; o < 1024; o <<= 1) {
        int t = (tid >= o) ? tmp[tid - o] : 0;
        __syncthreads();
        tmp[tid] += t;
        __syncthreads();
    }
    if (i < N_NODES) incl[i] = tmp[tid];
    if (tid == 1023) bsum[blockIdx.x] = tmp[1023];
}

__global__ void scan3_kernel(const int* __restrict__ deg, const int* __restrict__ incl,
                             const int* __restrict__ bsum,
                             int* __restrict__ off, int* __restrict__ cursor,
                             unsigned short* __restrict__ esrc)
{
    __shared__ int sb[NB_SCAN + 1];
    int tid = threadIdx.x;
    if (tid < 64) {
        int v = (tid < NB_SCAN) ? bsum[tid] : 0;
        int orig = v;
        #pragma unroll
        for (int o = 1; o < 64; o <<= 1) {
            int t = __shfl_up(v, o, 64);
            if (tid >= o) v += t;
        }
        if (tid < NB_SCAN) sb[tid] = v - orig;   // exclusive
        if (tid == 63)     sb[NB_SCAN] = v;      // grand total
    }
    __syncthreads();
    if (blockIdx.x == 0 && tid < 16) esrc[ET + tid] = 0;   // pad (safe over-reads)
    int i = blockIdx.x * blockDim.x + tid;
    if (i < N_NODES) {
        int e = incl[i] - deg[i] + sb[i >> 10];
        off[i] = e;
        cursor[i] = e;
    } else if (i == N_NODES) {
        off[N_NODES] = sb[NB_SCAN];
    }
}

// ===== MFMA dual GEMM, 1-term bf16 (32 rows x 64 cols/wave) + optional CSR scatter ===
// esrc is ushort (src < 65536): 1.7 MB array stays L2-resident -> kills the 64B-line
// write amplification that made the scatter 54 MB of HBM writes.
template <bool WITH_SCATTER>
__global__ __launch_bounds__(256, 2)
void gemm_mfma_kernel(const unsigned short* __restrict__ hhi,
                      const unsigned short* __restrict__ wlh,
                      const unsigned short* __restrict__ wrh,
                      const float* __restrict__ bl, const float* __restrict__ br,
                      const float* __restrict__ att,
                      unsigned short* __restrict__ xlb, unsigned short* __restrict__ xrb,
                      float* __restrict__ bs2,
                      const int* __restrict__ srcp, const int* __restrict__ dstp,
                      int* __restrict__ cursor, unsigned short* __restrict__ esrc, int n)
{
    if (WITH_SCATTER && blockIdx.x >= GEMM_BLOCKS) {
        int e = (blockIdx.x - GEMM_BLOCKS) * 256 + threadIdx.x;
        if (e < ET) {
            int s, dt;
            if (e < N_EDGES) { s = srcp[e]; dt = dstp[e]; }
            else             { s = e - N_EDGES; dt = s; }
            int pos = atomicAdd(cursor + dt, 1);
            esrc[pos] = (unsigned short)s;
        }
        return;
    }

    int lane = threadIdx.x & 63;
    int wid  = threadIdx.x >> 6;          // 0..3
    int rowB = blockIdx.x >> 1;
    int half = blockIdx.x & 1;
    int c0   = half * 64;                 // column half
    int m0   = (rowB * 4 + wid) * 32;     // this wave's 32 rows
    if (m0 >= n) return;
    int gl = lane & 15;
    int kg = lane >> 4;

    float blc[4], brc[4], attc[4];
    #pragma unroll
    for (int t = 0; t < 4; t++) {
        blc[t]  = bl [c0 + t * 16 + gl];
        brc[t]  = br [c0 + t * 16 + gl];
        attc[t] = att[c0 + t * 16 + gl];
    }

    int ar0 = m0 + gl;      if (ar0 >= n) ar0 = n - 1;
    int ar1 = m0 + 16 + gl; if (ar1 >= n) ar1 = n - 1;
    const unsigned short* ah0 = hhi + (size_t)ar0 * D + kg * 8;
    const unsigned short* ah1 = hhi + (size_t)ar1 * D + kg * 8;

    bf16x8 Ah0[4], Ah1[4];
    #pragma unroll
    for (int ks = 0; ks < 4; ks++) {
        Ah0[ks] = *(const bf16x8*)(ah0 + ks * 32);
        Ah1[ks] = *(const bf16x8*)(ah1 + ks * 32);
    }

    f32x4 accl[2][4], accr[2][4];
    #pragma unroll
    for (int rt = 0; rt < 2; rt++)
        #pragma unroll
        for (int t = 0; t < 4; t++) {
            accl[rt][t] = (f32x4){0.f, 0.f, 0.f, 0.f};
            accr[rt][t] = (f32x4){0.f, 0.f, 0.f, 0.f};
        }

    #pragma unroll
    for (int ks = 0; ks < 4; ks++) {
        #pragma unroll
        for (int t = 0; t < 4; t++) {
            size_t boff = (size_t)(c0 + t * 16 + gl) * D + kg * 8 + ks * 32;
            bf16x8 bLH = *(const bf16x8*)(wlh + boff);
            bf16x8 bRH = *(const bf16x8*)(wrh + boff);
            accl[0][t] = __builtin_amdgcn_mfma_f32_16x16x32_bf16(Ah0[ks], bLH, accl[0][t], 0, 0, 0);
            accr[0][t] = __builtin_amdgcn_mfma_f32_16x16x32_bf16(Ah0[ks], bRH, accr[0][t], 0, 0, 0);
            accl[1][t] = __builtin_amdgcn_mfma_f32_16x16x32_bf16(Ah1[ks], bLH, accl[1][t], 0, 0, 0);
            accr[1][t] = __builtin_amdgcn_mfma_f32_16x16x32_bf16(Ah1[ks], bRH, accr[1][t], 0, 0, 0);
        }
    }

    // epilogue (C/D: col = lane&15, row = (lane>>4)*4 + reg) + bs half store
    #pragma unroll
    for (int rt = 0; rt < 2; rt++) {
        #pragma unroll
        for (int r = 0; r < 4; r++) {
            int row = m0 + rt * 16 + kg * 4 + r;
            if (row < n) {
                float p = 0.f;
                #pragma unroll
                for (int t = 0; t < 4; t++) {
                    int col = c0 + t * 16 + gl;
                    float vl = accl[rt][t][r] + blc[t];
                    xlb[(size_t)row * D + col] = f2bf_rne(vl);
                    xrb[(size_t)row * D + col] = f2bf_rne(accr[rt][t][r] + brc[t]);
                    p = fmaf(attc[t], vl, p);
                }
                p += __shfl_xor(p, 1, 64);
                p += __shfl_xor(p, 2, 64);
                p += __shfl_xor(p, 4, 64);
                p += __shfl_xor(p, 8, 64);
                if (gl == 0) bs2[row * 2 + half] = 0.6f * LOG2E * p;
            }
        }
    }
}

// ===== fused per-node GATv2: 16 lanes/edge, 2 edges/group/iter, exp2-rebased =========
// score = bs2[s].x + bs2[s].y + sum(aav*|xl_s+xr_d|),  aav pre-scaled by 0.4*LOG2E.
// Packed f32x2 for x+r adds and acc updates (v_pk_*); score fma scalar (free |.|).
template <int LAST>
__global__ void node_attn_kernel(const unsigned short* __restrict__ xlb,
                                 const unsigned short* __restrict__ xrb,
                                 const float* __restrict__ bs2,
                                 const float* __restrict__ att,
                                 const float* __restrict__ bias,
                                 const int* __restrict__ off,
                                 const unsigned short* __restrict__ esrc,
                                 float* __restrict__ outF,
                                 unsigned short* __restrict__ hhi)
{
    int i    = (int)((blockIdx.x * (size_t)blockDim.x + threadIdx.x) >> 6);
    int lane = threadIdx.x & 63;
    if (i >= N_NODES) return;
    int g  = lane >> 4;     // edge-pair slot 0..3
    int gl = lane & 15;     // lane within group
    int fb = gl * 8;        // this lane's 8 features

    float aav[8];
    f32x2 rr2[4];
    {
        float4 a0 = *(const float4*)(att + fb);
        float4 a1 = *(const float4*)(att + fb + 4);
        const float s = 0.4f * LOG2E;
        aav[0] = s * a0.x; aav[1] = s * a0.y; aav[2] = s * a0.z; aav[3] = s * a0.w;
        aav[4] = s * a1.x; aav[5] = s * a1.y; aav[6] = s * a1.z; aav[7] = s * a1.w;
        uint4 r4 = *(const uint4*)(xrb + (size_t)i * D + fb);
        rr2[0] = unpack_bf2(r4.x); rr2[1] = unpack_bf2(r4.y);
        rr2[2] = unpack_bf2(r4.z); rr2[3] = unpack_bf2(r4.w);
    }

    float m = -1e30f, l = 0.f;
    f32x2 acc2[4];
    #pragma unroll
    for (int j = 0; j < 4; j++) acc2[j] = (f32x2){0.f, 0.f};

    int k    = off[i];
    int kEnd = off[i + 1];

    int ka = k + g, kb = k + 4 + g;
    bool va = ka < kEnd, vb = kb < kEnd;
    int sa = esrc[ka];                      // padded: over-read safe
    int sb = esrc[kb];
    uint4 x4a = *(const uint4*)(xlb + (size_t)sa * D + fb);
    uint4 x4b = *(const uint4*)(xlb + (size_t)sb * D + fb);
    float2 ba2 = *(const float2*)(bs2 + sa * 2);
    float2 bb2 = *(const float2*)(bs2 + sb * 2);
    float bsa = ba2.x + ba2.y, bsb = bb2.x + bb2.y;

    while (k < kEnd) {
        int kn = k + 8;
        uint4 nxa = x4a, nxb = x4b;
        float nbsa = bsa, nbsb = bsb;
        bool nva = false, nvb = false;
        if (kn < kEnd) {                    // wave-uniform prefetch
            int nka = kn + g, nkb = kn + 4 + g;
            nva = nka < kEnd; nvb = nkb < kEnd;
            int nsa = esrc[nka];
            int nsb = esrc[nkb];
            nxa = *(const uint4*)(xlb + (size_t)nsa * D + fb);
            nxb = *(const uint4*)(xlb + (size_t)nsb * D + fb);
            float2 na2 = *(const float2*)(bs2 + nsa * 2);
            float2 nb2 = *(const float2*)(bs2 + nsb * 2);
            nbsa = na2.x + na2.y; nbsb = nb2.x + nb2.y;
        }
        f32x2 xa2[4], xb2[4];
        xa2[0] = unpack_bf2(x4a.x); xa2[1] = unpack_bf2(x4a.y);
        xa2[2] = unpack_bf2(x4a.z); xa2[3] = unpack_bf2(x4a.w);
        xb2[0] = unpack_bf2(x4b.x); xb2[1] = unpack_bf2(x4b.y);
        xb2[2] = unpack_bf2(x4b.z); xb2[3] = unpack_bf2(x4b.w);

        float s2a = 0.f, s2b = 0.f;
        #pragma unroll
        for (int q = 0; q < 4; q++) {
            f32x2 ta = xa2[q] + rr2[q];      // v_pk_add_f32
            f32x2 tb = xb2[q] + rr2[q];
            s2a = fmaf(aav[2*q],   fabsf(ta.x), s2a);   // scalar fma, free |.|
            s2a = fmaf(aav[2*q+1], fabsf(ta.y), s2a);
            s2b = fmaf(aav[2*q],   fabsf(tb.x), s2b);
            s2b = fmaf(aav[2*q+1], fabsf(tb.y), s2b);
        }
        s2a += __shfl_xor(s2a, 1, 64);
        s2b += __shfl_xor(s2b, 1, 64);
        s2a += __shfl_xor(s2a, 2, 64);
        s2b += __shfl_xor(s2b, 2, 64);
        s2a += __shfl_xor(s2a, 4, 64);
        s2b += __shfl_xor(s2b, 4, 64);
        s2a += __shfl_xor(s2a, 8, 64);
        s2b += __shfl_xor(s2b, 8, 64);
        float sca = bsa + s2a;
        float scb = bsb + s2b;
        float mx2 = fmaxf(sca, scb);
        if (__any(mx2 > m + DEFER_THR)) {
            float mn = fmaxf(m, mx2);
            float f  = exp2f(m - mn);
            float pa = va ? exp2f(sca - mn) : 0.f;
            float pb = vb ? exp2f(scb - mn) : 0.f;
            l = l * f + pa + pb;
            f32x2 fv = {f, f}, pa2 = {pa, pa}, pb2 = {pb, pb};
            #pragma unroll
            for (int q = 0; q < 4; q++)
                acc2[q] = __builtin_elementwise_fma(acc2[q], fv,
                          __builtin_elementwise_fma(xa2[q], pa2, xb2[q] * pb2));
            m = mn;
        } else {
            float pa = va ? exp2f(sca - m) : 0.f;
            float pb = vb ? exp2f(scb - m) : 0.f;
            l += pa + pb;
            f32x2 pa2 = {pa, pa}, pb2 = {pb, pb};
            #pragma unroll
            for (int q = 0; q < 4; q++)
                acc2[q] = __builtin_elementwise_fma(xa2[q], pa2,
                          __builtin_elementwise_fma(xb2[q], pb2, acc2[q]));
        }
        x4a = nxa; x4b = nxb; bsa = nbsa; bsb = nbsb; va = nva; vb = nvb;
        k = kn;
    }

    // merge the 4 groups' online-softmax states (xor 16, then 32), log2 units
    #pragma unroll
    for (int o = 16; o <= 32; o <<= 1) {
        float mo  = __shfl_xor(m, o, 64);
        float lo2 = __shfl_xor(l, o, 64);
        float mn  = fmaxf(m, mo);
        float f1  = exp2f(m - mn);
        float f2s = exp2f(mo - mn);
        l = l * f1 + lo2 * f2s;
        f32x2 f1v = {f1, f1}, f2v = {f2s, f2s};
        #pragma unroll
        for (int q = 0; q < 4; q++) {
            f32x2 ao;
            ao.x = __shfl_xor(acc2[q].x, o, 64);
            ao.y = __shfl_xor(acc2[q].y, o, 64);
            acc2[q] = __builtin_elementwise_fma(acc2[q], f1v, ao * f2v);
        }
        m = mn;
    }

    float inv = 1.f / (l + 1e-16f);
    float hv[8];
    {
        float4 b0 = *(const float4*)(bias + fb);
        float4 b1 = *(const float4*)(bias + fb + 4);
        float bb[8] = {b0.x, b0.y, b0.z, b0.w, b1.x, b1.y, b1.z, b1.w};
        #pragma unroll
        for (int q = 0; q < 4; q++) {
            hv[2*q]   = fmaxf(fmaf(acc2[q].x, inv, bb[2*q]),   0.f);
            hv[2*q+1] = fmaxf(fmaf(acc2[q].y, inv, bb[2*q+1]), 0.f);
        }
    }

    if (LAST) {
        float mx = hv[0];
        #pragma unroll
        for (int j = 1; j < 8; j++) mx = fmaxf(mx, hv[j]);
        mx = fmaxf(mx, __shfl_xor(mx, 1, 64));
        mx = fmaxf(mx, __shfl_xor(mx, 2, 64));
        mx = fmaxf(mx, __shfl_xor(mx, 4, 64));
        mx = fmaxf(mx, __shfl_xor(mx, 8, 64));
        float se = 0.f;
        #pragma unroll
        for (int j = 0; j < 8; j++) se += __expf(hv[j] - mx);
        se += __shfl_xor(se, 1, 64);
        se += __shfl_xor(se, 2, 64);
        se += __shfl_xor(se, 4, 64);
        se += __shfl_xor(se, 8, 64);
        float ls = logf(se) + mx;
        if (g == 0) {
            float4 o0 = make_float4(hv[0] - ls, hv[1] - ls, hv[2] - ls, hv[3] - ls);
            float4 o1 = make_float4(hv[4] - ls, hv[5] - ls, hv[6] - ls, hv[7] - ls);
            float* dst = outF + (size_t)i * D + fb;
            *(float4*)(dst)     = o0;
            *(float4*)(dst + 4) = o1;
        }
    } else {
        if (g == 0) {
            unsigned pk[4];
            #pragma unroll
            for (int j = 0; j < 4; j++) {
                pk[j] = (unsigned)f2bf_rne(hv[j * 2]) |
                        ((unsigned)f2bf_rne(hv[j * 2 + 1]) << 16);
            }
            unsigned short* dst = hhi + (size_t)i * D + fb;
            *(uint4*)dst = make_uint4(pk[0], pk[1], pk[2], pk[3]);
        }
    }
}

extern "C" void kernel_launch(void* const* d_in, const int* in_sizes, int n_in,
                              void* d_out, int out_size, void* d_ws, size_t ws_size,
                              hipStream_t stream)
{
    const float* x    = (const float*)d_in[0];
    const int*   ei   = (const int*)  d_in[1];
    const float* Wl   = (const float*)d_in[2];
    const float* bl   = (const float*)d_in[3];
    const float* Wr   = (const float*)d_in[4];
    const float* br   = (const float*)d_in[5];
    const float* att  = (const float*)d_in[6];
    const float* bias = (const float*)d_in[7];
    float* out = (float*)d_out;

    const int* srcp = ei;
    const int* dstp = ei + N_EDGES;

    const size_t ND = (size_t)N_NODES * D;
    const size_t WSZ = (size_t)NLAYERS * D * D;
    char* ws = (char*)d_ws;
    unsigned short* xlb = (unsigned short*)ws; ws += ND * sizeof(unsigned short);
    unsigned short* xrb = (unsigned short*)ws; ws += ND * sizeof(unsigned short);
    unsigned short* hhi = (unsigned short*)ws; ws += ND * sizeof(unsigned short);
    unsigned short* wlh = (unsigned short*)ws; ws += WSZ * sizeof(unsigned short);
    unsigned short* wrh = (unsigned short*)ws; ws += WSZ * sizeof(unsigned short);
    float* bs2  = (float*)ws; ws += (size_t)N_NODES * 2 * sizeof(float);
    int* deg    = (int*)ws;  ws += (size_t)N_NODES * sizeof(int);
    int* incl   = (int*)ws;  ws += (size_t)N_NODES * sizeof(int);
    int* off    = (int*)ws;  ws += (size_t)(N_NODES + 1) * sizeof(int);
    int* cursor = (int*)ws;  ws += (size_t)N_NODES * sizeof(int);
    int* bsum   = (int*)ws;  ws += (size_t)NB_SCAN * sizeof(int);
    unsigned short* esrc = (unsigned short*)ws; ws += ((size_t)ET + 16) * sizeof(unsigned short);

    const int prepGrid  = (int)((ND / 4 + 255) / 256);
    const int nodeGrid  = (N_NODES + 3) / 4;
    const int scan3Grid = (N_NODES + 1 + 255) / 256;

    hipMemsetAsync(deg, 0, (size_t)N_NODES * sizeof(int), stream);
    prep_kernel<<<prepGrid, 256, 0, stream>>>(x, Wl, Wr, dstp, hhi, wlh, wrh, deg);

    scan1_kernel<<<NB_SCAN, 1024, 0, stream>>>(deg, incl, bsum);
    scan3_kernel<<<scan3Grid, 256, 0, stream>>>(deg, incl, bsum, off, cursor, esrc);

    for (int l = 0; l < NLAYERS; l++) {
        size_t wOff = (size_t)l * D * D;
        if (l == 0) {
            gemm_mfma_kernel<true><<<GEMM_BLOCKS + EDGE_BLOCKS, 256, 0, stream>>>(
                hhi, wlh + wOff, wrh + wOff,
                bl + (size_t)l * D, br + (size_t)l * D, att + (size_t)l * D,
                xlb, xrb, bs2, srcp, dstp, cursor, esrc, N_NODES);
        } else {
            gemm_mfma_kernel<false><<<GEMM_BLOCKS, 256, 0, stream>>>(
                hhi, wlh + wOff, wrh + wOff,
                bl + (size_t)l * D, br + (size_t)l * D, att + (size_t)l * D,
                xlb, xrb, bs2, nullptr, nullptr, nullptr, nullptr, N_NODES);
        }

        if (l == NLAYERS - 1) {
            node_attn_kernel<1><<<nodeGrid, 256, 0, stream>>>(
                xlb, xrb, bs2, att + (size_t)l * D, bias + (size_t)l * D,
                off, esrc, out, nullptr);
        } else {
            node_attn_kernel<0><<<nodeGrid, 256, 0, stream>>>(
                xlb, xrb, bs2, att + (size_t)l * D, bias + (size_t)l * D,
                off, esrc, nullptr, hhi);
        }
    }
}

// Round 15
// 307.507 us; speedup vs baseline: 1.3592x; 1.0628x over previous
//
#include <hip/hip_runtime.h>
#include <cstdint>
#include <cstddef>

#define N_NODES 50000
#define N_EDGES 800000
#define ET (N_EDGES + N_NODES)   // edges + self loops
#define D 128
#define NLAYERS 3
#define LOG2E 1.44269504f
#define DEFER_THR 11.5415603f    // 8 nats in log2 units
#define NB_SCAN ((N_NODES + 1023) / 1024)   // 49 blocks
#define GEMM_BLOCKS (((N_NODES + 127) / 128) * 2)   // 782
#define EDGE_BLOCKS ((ET + 255) / 256)              // 3321
#define BPAD 136                  // padded LDS row (128 + 8 bf16) -> ~2-way banks only

typedef __bf16 bf16x8 __attribute__((ext_vector_type(8)));
typedef float  f32x4  __attribute__((ext_vector_type(4)));
typedef float  f32x2  __attribute__((ext_vector_type(2)));

__device__ __forceinline__ unsigned short f2bf_rne(float v) {
    unsigned u = __float_as_uint(v);
    u += 0x7fffu + ((u >> 16) & 1u);
    return (unsigned short)(u >> 16);
}
__device__ __forceinline__ f32x2 unpack_bf2(unsigned u) {
    f32x2 r;
    r.x = __uint_as_float(u << 16);
    r.y = __uint_as_float(u & 0xffff0000u);
    return r;
}

// ===== merged prep: x -> bf16, transpose weights -> bf16, degree count ==============
__global__ void prep_kernel(const float* __restrict__ x,
                            const float* __restrict__ Wl,
                            const float* __restrict__ Wr,
                            const int* __restrict__ dstp,
                            unsigned short* __restrict__ hhi,
                            unsigned short* __restrict__ wlh,
                            unsigned short* __restrict__ wrh,
                            int* __restrict__ deg)
{
    int idx = blockIdx.x * blockDim.x + threadIdx.x;
    if (idx < (N_NODES * D) / 4) {
        float4 v = ((const float4*)x)[idx];
        uint2 hw;
        hw.x = (unsigned)f2bf_rne(v.x) | ((unsigned)f2bf_rne(v.y) << 16);
        hw.y = (unsigned)f2bf_rne(v.z) | ((unsigned)f2bf_rne(v.w) << 16);
        ((uint2*)hhi)[idx] = hw;
    }
    if (idx < NLAYERS * D * D) {
        int l   = idx / (D * D);
        int rem = idx - l * D * D;
        int kk  = rem / D;
        int nn  = rem - kk * D;
        int tp  = l * D * D + nn * D + kk;
        wlh[tp] = f2bf_rne(Wl[idx]);
        wrh[tp] = f2bf_rne(Wr[idx]);
    }
    if (idx < ET) {
        int dt = (idx < N_EDGES) ? dstp[idx] : idx - N_EDGES;
        atomicAdd(deg + dt, 1);
    }
}

// ================= CSR build ==================
__global__ void scan1_kernel(const int* __restrict__ deg,
                             int* __restrict__ incl, int* __restrict__ bsum)
{
    __shared__ int tmp[1024];
    int tid = threadIdx.x;
    int i = blockIdx.x * 1024 + tid;
    int v = (i < N_NODES) ? deg[i] : 0;
    tmp[tid] = v;
    __syncthreads();
    #pragma unroll
    for (int o = 1; o < 1024; o <<= 1) {
        int t = (tid >= o) ? tmp[tid - o] : 0;
        __syncthreads();
        tmp[tid] += t;
        __syncthreads();
    }
    if (i < N_NODES) incl[i] = tmp[tid];
    if (tid == 1023) bsum[blockIdx.x] = tmp[1023];
}

__global__ void scan3_kernel(const int* __restrict__ deg, const int* __restrict__ incl,
                             const int* __restrict__ bsum,
                             int* __restrict__ off, int* __restrict__ cursor,
                             unsigned short* __restrict__ esrc)
{
    __shared__ int sb[NB_SCAN + 1];
    int tid = threadIdx.x;
    if (tid < 64) {
        int v = (tid < NB_SCAN) ? bsum[tid] : 0;
        int orig = v;
        #pragma unroll
        for (int o = 1; o < 64; o <<= 1) {
            int t = __shfl_up(v, o, 64);
            if (tid >= o) v += t;
        }
        if (tid < NB_SCAN) sb[tid] = v - orig;   // exclusive
        if (tid == 63)     sb[NB_SCAN] = v;      // grand total
    }
    __syncthreads();
    if (blockIdx.x == 0 && tid < 16) esrc[ET + tid] = 0;   // pad (safe over-reads)
    int i = blockIdx.x * blockDim.x + tid;
    if (i < N_NODES) {
        int e = incl[i] - deg[i] + sb[i >> 10];
        off[i] = e;
        cursor[i] = e;
    } else if (i == N_NODES) {
        off[N_NODES] = sb[NB_SCAN];
    }
}

// ===== MFMA dual GEMM, 1-term bf16, LDS-staged B + optional fused CSR scatter ========
// Block: 4 waves, 128 rows x 64-col half. B half (both arrays) staged in LDS once,
// coalesced; fragments via ds_read (padded rows -> ~2-way banks). 4 blocks/CU.
template <bool WITH_SCATTER>
__global__ __launch_bounds__(256, 4)
void gemm_mfma_kernel(const unsigned short* __restrict__ hhi,
                      const unsigned short* __restrict__ wlh,
                      const unsigned short* __restrict__ wrh,
                      const float* __restrict__ bl, const float* __restrict__ br,
                      const float* __restrict__ att,
                      unsigned short* __restrict__ xlb, unsigned short* __restrict__ xrb,
                      float* __restrict__ bs2,
                      const int* __restrict__ srcp, const int* __restrict__ dstp,
                      int* __restrict__ cursor, unsigned short* __restrict__ esrc, int n)
{
    if (WITH_SCATTER && blockIdx.x >= GEMM_BLOCKS) {
        int e = (blockIdx.x - GEMM_BLOCKS) * 256 + threadIdx.x;
        if (e < ET) {
            int s, dt;
            if (e < N_EDGES) { s = srcp[e]; dt = dstp[e]; }
            else             { s = e - N_EDGES; dt = s; }
            int pos = atomicAdd(cursor + dt, 1);
            esrc[pos] = (unsigned short)s;
        }
        return;
    }

    __shared__ unsigned short lb[64][BPAD];   // 17 KiB
    __shared__ unsigned short rb[64][BPAD];   // 17 KiB

    int lane = threadIdx.x & 63;
    int wid  = threadIdx.x >> 6;          // 0..3
    int rowB = blockIdx.x >> 1;
    int half = blockIdx.x & 1;
    int c0   = half * 64;                 // column half
    int m0   = (rowB * 4 + wid) * 32;     // this wave's 32 rows
    int gl = lane & 15;
    int kg = lane >> 4;

    // ---- stage B half into LDS (fully coalesced 16B chunks) ----
    {
        const uint4* gl4 = (const uint4*)(wlh + (size_t)c0 * D);   // 64 rows x 128 k
        const uint4* gr4 = (const uint4*)(wrh + (size_t)c0 * D);
        #pragma unroll
        for (int c = 0; c < 4; c++) {
            int idx = c * 256 + threadIdx.x;   // 0..1023 16B-chunks
            int row = idx >> 4;
            int kc  = idx & 15;
            *(uint4*)&lb[row][kc * 8] = gl4[idx];
            *(uint4*)&rb[row][kc * 8] = gr4[idx];
        }
    }
    __syncthreads();
    if (m0 >= n) return;                  // after barrier (all waves participated)

    float blc[4], brc[4], attc[4];
    #pragma unroll
    for (int t = 0; t < 4; t++) {
        blc[t]  = bl [c0 + t * 16 + gl];
        brc[t]  = br [c0 + t * 16 + gl];
        attc[t] = att[c0 + t * 16 + gl];
    }

    int ar0 = m0 + gl;      if (ar0 >= n) ar0 = n - 1;
    int ar1 = m0 + 16 + gl; if (ar1 >= n) ar1 = n - 1;
    const unsigned short* ah0 = hhi + (size_t)ar0 * D + kg * 8;
    const unsigned short* ah1 = hhi + (size_t)ar1 * D + kg * 8;

    bf16x8 Ah0[4], Ah1[4];
    #pragma unroll
    for (int ks = 0; ks < 4; ks++) {
        Ah0[ks] = *(const bf16x8*)(ah0 + ks * 32);
        Ah1[ks] = *(const bf16x8*)(ah1 + ks * 32);
    }

    f32x4 accl[2][4], accr[2][4];
    #pragma unroll
    for (int rt = 0; rt < 2; rt++)
        #pragma unroll
        for (int t = 0; t < 4; t++) {
            accl[rt][t] = (f32x4){0.f, 0.f, 0.f, 0.f};
            accr[rt][t] = (f32x4){0.f, 0.f, 0.f, 0.f};
        }

    #pragma unroll
    for (int ks = 0; ks < 4; ks++) {
        #pragma unroll
        for (int t = 0; t < 4; t++) {
            int brow = t * 16 + gl;
            int kofs = kg * 8 + ks * 32;
            bf16x8 bLH = *(const bf16x8*)&lb[brow][kofs];
            bf16x8 bRH = *(const bf16x8*)&rb[brow][kofs];
            accl[0][t] = __builtin_amdgcn_mfma_f32_16x16x32_bf16(Ah0[ks], bLH, accl[0][t], 0, 0, 0);
            accr[0][t] = __builtin_amdgcn_mfma_f32_16x16x32_bf16(Ah0[ks], bRH, accr[0][t], 0, 0, 0);
            accl[1][t] = __builtin_amdgcn_mfma_f32_16x16x32_bf16(Ah1[ks], bLH, accl[1][t], 0, 0, 0);
            accr[1][t] = __builtin_amdgcn_mfma_f32_16x16x32_bf16(Ah1[ks], bRH, accr[1][t], 0, 0, 0);
        }
    }

    // epilogue (C/D: col = lane&15, row = (lane>>4)*4 + reg) + bs half store
    #pragma unroll
    for (int rt = 0; rt < 2; rt++) {
        #pragma unroll
        for (int r = 0; r < 4; r++) {
            int row = m0 + rt * 16 + kg * 4 + r;
            if (row < n) {
                float p = 0.f;
                #pragma unroll
                for (int t = 0; t < 4; t++) {
                    int col = c0 + t * 16 + gl;
                    float vl = accl[rt][t][r] + blc[t];
                    xlb[(size_t)row * D + col] = f2bf_rne(vl);
                    xrb[(size_t)row * D + col] = f2bf_rne(accr[rt][t][r] + brc[t]);
                    p = fmaf(attc[t], vl, p);
                }
                p += __shfl_xor(p, 1, 64);
                p += __shfl_xor(p, 2, 64);
                p += __shfl_xor(p, 4, 64);
                p += __shfl_xor(p, 8, 64);
                if (gl == 0) bs2[row * 2 + half] = 0.6f * LOG2E * p;
            }
        }
    }
}

// ===== fused per-node GATv2: 16 lanes/edge, 2 edges/group/iter, exp2-rebased =========
// score = bs2[s].x + bs2[s].y + sum(aav*|xl_s+xr_d|),  aav pre-scaled by 0.4*LOG2E.
template <int LAST>
__global__ void node_attn_kernel(const unsigned short* __restrict__ xlb,
                                 const unsigned short* __restrict__ xrb,
                                 const float* __restrict__ bs2,
                                 const float* __restrict__ att,
                                 const float* __restrict__ bias,
                                 const int* __restrict__ off,
                                 const unsigned short* __restrict__ esrc,
                                 float* __restrict__ outF,
                                 unsigned short* __restrict__ hhi)
{
    int i    = (int)((blockIdx.x * (size_t)blockDim.x + threadIdx.x) >> 6);
    int lane = threadIdx.x & 63;
    if (i >= N_NODES) return;
    int g  = lane >> 4;     // edge-pair slot 0..3
    int gl = lane & 15;     // lane within group
    int fb = gl * 8;        // this lane's 8 features

    float aav[8];
    f32x2 rr2[4];
    {
        float4 a0 = *(const float4*)(att + fb);
        float4 a1 = *(const float4*)(att + fb + 4);
        const float s = 0.4f * LOG2E;
        aav[0] = s * a0.x; aav[1] = s * a0.y; aav[2] = s * a0.z; aav[3] = s * a0.w;
        aav[4] = s * a1.x; aav[5] = s * a1.y; aav[6] = s * a1.z; aav[7] = s * a1.w;
        uint4 r4 = *(const uint4*)(xrb + (size_t)i * D + fb);
        rr2[0] = unpack_bf2(r4.x); rr2[1] = unpack_bf2(r4.y);
        rr2[2] = unpack_bf2(r4.z); rr2[3] = unpack_bf2(r4.w);
    }

    float m = -1e30f, l = 0.f;
    f32x2 acc2[4];
    #pragma unroll
    for (int j = 0; j < 4; j++) acc2[j] = (f32x2){0.f, 0.f};

    int k    = off[i];
    int kEnd = off[i + 1];

    int ka = k + g, kb = k + 4 + g;
    bool va = ka < kEnd, vb = kb < kEnd;
    int sa = esrc[ka];                      // padded: over-read safe
    int sb = esrc[kb];
    uint4 x4a = *(const uint4*)(xlb + (size_t)sa * D + fb);
    uint4 x4b = *(const uint4*)(xlb + (size_t)sb * D + fb);
    float2 ba2 = *(const float2*)(bs2 + sa * 2);
    float2 bb2 = *(const float2*)(bs2 + sb * 2);
    float bsa = ba2.x + ba2.y, bsb = bb2.x + bb2.y;

    while (k < kEnd) {
        int kn = k + 8;
        uint4 nxa = x4a, nxb = x4b;
        float nbsa = bsa, nbsb = bsb;
        bool nva = false, nvb = false;
        if (kn < kEnd) {                    // wave-uniform prefetch
            int nka = kn + g, nkb = kn + 4 + g;
            nva = nka < kEnd; nvb = nkb < kEnd;
            int nsa = esrc[nka];
            int nsb = esrc[nkb];
            nxa = *(const uint4*)(xlb + (size_t)nsa * D + fb);
            nxb = *(const uint4*)(xlb + (size_t)nsb * D + fb);
            float2 na2 = *(const float2*)(bs2 + nsa * 2);
            float2 nb2 = *(const float2*)(bs2 + nsb * 2);
            nbsa = na2.x + na2.y; nbsb = nb2.x + nb2.y;
        }
        f32x2 xa2[4], xb2[4];
        xa2[0] = unpack_bf2(x4a.x); xa2[1] = unpack_bf2(x4a.y);
        xa2[2] = unpack_bf2(x4a.z); xa2[3] = unpack_bf2(x4a.w);
        xb2[0] = unpack_bf2(x4b.x); xb2[1] = unpack_bf2(x4b.y);
        xb2[2] = unpack_bf2(x4b.z); xb2[3] = unpack_bf2(x4b.w);

        float s2a = 0.f, s2b = 0.f;
        #pragma unroll
        for (int q = 0; q < 4; q++) {
            f32x2 ta = xa2[q] + rr2[q];      // v_pk_add_f32
            f32x2 tb = xb2[q] + rr2[q];
            s2a = fmaf(aav[2*q],   fabsf(ta.x), s2a);
            s2a = fmaf(aav[2*q+1], fabsf(ta.y), s2a);
            s2b = fmaf(aav[2*q],   fabsf(tb.x), s2b);
            s2b = fmaf(aav[2*q+1], fabsf(tb.y), s2b);
        }
        s2a += __shfl_xor(s2a, 1, 64);
        s2b += __shfl_xor(s2b, 1, 64);
        s2a += __shfl_xor(s2a, 2, 64);
        s2b += __shfl_xor(s2b, 2, 64);
        s2a += __shfl_xor(s2a, 4, 64);
        s2b += __shfl_xor(s2b, 4, 64);
        s2a += __shfl_xor(s2a, 8, 64);
        s2b += __shfl_xor(s2b, 8, 64);
        float sca = bsa + s2a;
        float scb = bsb + s2b;
        float mx2 = fmaxf(sca, scb);
        if (__any(mx2 > m + DEFER_THR)) {
            float mn = fmaxf(m, mx2);
            float f  = exp2f(m - mn);
            float pa = va ? exp2f(sca - mn) : 0.f;
            float pb = vb ? exp2f(scb - mn) : 0.f;
            l = l * f + pa + pb;
            f32x2 fv = {f, f}, pa2 = {pa, pa}, pb2 = {pb, pb};
            #pragma unroll
            for (int q = 0; q < 4; q++)
                acc2[q] = __builtin_elementwise_fma(acc2[q], fv,
                          __builtin_elementwise_fma(xa2[q], pa2, xb2[q] * pb2));
            m = mn;
        } else {
            float pa = va ? exp2f(sca - m) : 0.f;
            float pb = vb ? exp2f(scb - m) : 0.f;
            l += pa + pb;
            f32x2 pa2 = {pa, pa}, pb2 = {pb, pb};
            #pragma unroll
            for (int q = 0; q < 4; q++)
                acc2[q] = __builtin_elementwise_fma(xa2[q], pa2,
                          __builtin_elementwise_fma(xb2[q], pb2, acc2[q]));
        }
        x4a = nxa; x4b = nxb; bsa = nbsa; bsb = nbsb; va = nva; vb = nvb;
        k = kn;
    }

    // merge the 4 groups' online-softmax states (xor 16, then 32), log2 units
    #pragma unroll
    for (int o = 16; o <= 32; o <<= 1) {
        float mo  = __shfl_xor(m, o, 64);
        float lo2 = __shfl_xor(l, o, 64);
        float mn  = fmaxf(m, mo);
        float f1  = exp2f(m - mn);
        float f2s = exp2f(mo - mn);
        l = l * f1 + lo2 * f2s;
        f32x2 f1v = {f1, f1}, f2v = {f2s, f2s};
        #pragma unroll
        for (int q = 0; q < 4; q++) {
            f32x2 ao;
            ao.x = __shfl_xor(acc2[q].x, o, 64);
            ao.y = __shfl_xor(acc2[q].y, o, 64);
            acc2[q] = __builtin_elementwise_fma(acc2[q], f1v, ao * f2v);
        }
        m = mn;
    }

    float inv = 1.f / (l + 1e-16f);
    float hv[8];
    {
        float4 b0 = *(const float4*)(bias + fb);
        float4 b1 = *(const float4*)(bias + fb + 4);
        float bb[8] = {b0.x, b0.y, b0.z, b0.w, b1.x, b1.y, b1.z, b1.w};
        #pragma unroll
        for (int q = 0; q < 4; q++) {
            hv[2*q]   = fmaxf(fmaf(acc2[q].x, inv, bb[2*q]),   0.f);
            hv[2*q+1] = fmaxf(fmaf(acc2[q].y, inv, bb[2*q+1]), 0.f);
        }
    }

    if (LAST) {
        float mx = hv[0];
        #pragma unroll
        for (int j = 1; j < 8; j++) mx = fmaxf(mx, hv[j]);
        mx = fmaxf(mx, __shfl_xor(mx, 1, 64));
        mx = fmaxf(mx, __shfl_xor(mx, 2, 64));
        mx = fmaxf(mx, __shfl_xor(mx, 4, 64));
        mx = fmaxf(mx, __shfl_xor(mx, 8, 64));
        float se = 0.f;
        #pragma unroll
        for (int j = 0; j < 8; j++) se += __expf(hv[j] - mx);
        se += __shfl_xor(se, 1, 64);
        se += __shfl_xor(se, 2, 64);
        se += __shfl_xor(se, 4, 64);
        se += __shfl_xor(se, 8, 64);
        float ls = logf(se) + mx;
        if (g == 0) {
            float4 o0 = make_float4(hv[0] - ls, hv[1] - ls, hv[2] - ls, hv[3] - ls);
            float4 o1 = make_float4(hv[4] - ls, hv[5] - ls, hv[6] - ls, hv[7] - ls);
            float* dst = outF + (size_t)i * D + fb;
            *(float4*)(dst)     = o0;
            *(float4*)(dst + 4) = o1;
        }
    } else {
        if (g == 0) {
            unsigned pk[4];
            #pragma unroll
            for (int j = 0; j < 4; j++) {
                pk[j] = (unsigned)f2bf_rne(hv[j * 2]) |
                        ((unsigned)f2bf_rne(hv[j * 2 + 1]) << 16);
            }
            unsigned short* dst = hhi + (size_t)i * D + fb;
            *(uint4*)dst = make_uint4(pk[0], pk[1], pk[2], pk[3]);
        }
    }
}

extern "C" void kernel_launch(void* const* d_in, const int* in_sizes, int n_in,
                              void* d_out, int out_size, void* d_ws, size_t ws_size,
                              hipStream_t stream)
{
    const float* x    = (const float*)d_in[0];
    const int*   ei   = (const int*)  d_in[1];
    const float* Wl   = (const float*)d_in[2];
    const float* bl   = (const float*)d_in[3];
    const float* Wr   = (const float*)d_in[4];
    const float* br   = (const float*)d_in[5];
    const float* att  = (const float*)d_in[6];
    const float* bias = (const float*)d_in[7];
    float* out = (float*)d_out;

    const int* srcp = ei;
    const int* dstp = ei + N_EDGES;

    const size_t ND = (size_t)N_NODES * D;
    const size_t WSZ = (size_t)NLAYERS * D * D;
    char* ws = (char*)d_ws;
    unsigned short* xlb = (unsigned short*)ws; ws += ND * sizeof(unsigned short);
    unsigned short* xrb = (unsigned short*)ws; ws += ND * sizeof(unsigned short);
    unsigned short* hhi = (unsigned short*)ws; ws += ND * sizeof(unsigned short);
    unsigned short* wlh = (unsigned short*)ws; ws += WSZ * sizeof(unsigned short);
    unsigned short* wrh = (unsigned short*)ws; ws += WSZ * sizeof(unsigned short);
    float* bs2  = (float*)ws; ws += (size_t)N_NODES * 2 * sizeof(float);
    int* deg    = (int*)ws;  ws += (size_t)N_NODES * sizeof(int);
    int* incl   = (int*)ws;  ws += (size_t)N_NODES * sizeof(int);
    int* off    = (int*)ws;  ws += (size_t)(N_NODES + 1) * sizeof(int);
    int* cursor = (int*)ws;  ws += (size_t)N_NODES * sizeof(int);
    int* bsum   = (int*)ws;  ws += (size_t)NB_SCAN * sizeof(int);
    unsigned short* esrc = (unsigned short*)ws; ws += ((size_t)ET + 16) * sizeof(unsigned short);

    const int prepGrid  = (int)((ND / 4 + 255) / 256);
    const int nodeGrid  = (N_NODES + 3) / 4;
    const int scan3Grid = (N_NODES + 1 + 255) / 256;

    hipMemsetAsync(deg, 0, (size_t)N_NODES * sizeof(int), stream);
    prep_kernel<<<prepGrid, 256, 0, stream>>>(x, Wl, Wr, dstp, hhi, wlh, wrh, deg);

    scan1_kernel<<<NB_SCAN, 1024, 0, stream>>>(deg, incl, bsum);
    scan3_kernel<<<scan3Grid, 256, 0, stream>>>(deg, incl, bsum, off, cursor, esrc);

    for (int l = 0; l < NLAYERS; l++) {
        size_t wOff = (size_t)l * D * D;
        if (l == 0) {
            gemm_mfma_kernel<true><<<GEMM_BLOCKS + EDGE_BLOCKS, 256, 0, stream>>>(
                hhi, wlh + wOff, wrh + wOff,
                bl + (size_t)l * D, br + (size_t)l * D, att + (size_t)l * D,
                xlb, xrb, bs2, srcp, dstp, cursor, esrc, N_NODES);
        } else {
            gemm_mfma_kernel<false><<<GEMM_BLOCKS, 256, 0, stream>>>(
                hhi, wlh + wOff, wrh + wOff,
                bl + (size_t)l * D, br + (size_t)l * D, att + (size_t)l * D,
                xlb, xrb, bs2, nullptr, nullptr, nullptr, nullptr, N_NODES);
        }

        if (l == NLAYERS - 1) {
            node_attn_kernel<1><<<nodeGrid, 256, 0, stream>>>(
                xlb, xrb, bs2, att + (size_t)l * D, bias + (size_t)l * D,
                off, esrc, out, nullptr);
        } else {
            node_attn_kernel<0><<<nodeGrid, 256, 0, stream>>>(
                xlb, xrb, bs2, att + (size_t)l * D, bias + (size_t)l * D,
                off, esrc, nullptr, hhi);
        }
    }
}